// Round 1
// baseline (1577.777 us; speedup 1.0000x reference)
//
#include <hip/hip_runtime.h>

#define USER_NUM 100000
#define ITEM_NUM 50000
#define NN (USER_NUM + ITEM_NUM)
#define EMB 64
#define N_EDGES 8000000
#define EPS_C 0.1f
#define PROTO 4000

// ---------------- old-path params (kept verbatim as ws fallback) ----------------
#define BSHIFT 6
#define BROWS 64                                // rows per bucket
#define NB ((NN + BROWS - 1) / BROWS)           // 2344 buckets
#define NSUB 8
#define CAPS 608
#define WIN (NSUB * CAPS)
#define CAP 4608

// ---------------- new hierarchical multisplit params ----------------
#define SBSHIFT 9
#define SBROWS 512                              // rows per super-bin
#define NSB ((NN + SBROWS - 1) / SBROWS)        // 293 super-bins
#define SCAP 28160                              // slots/super-bin; mean 27304, +5.2 sigma
#define RING_D 24                               // L1 LDS ring depth per bin
#define CHUNK1 8                                // L1 flush granularity = 64 B line
#define GRID1 1024
#define EPB ((N_EDGES + GRID1 - 1) / GRID1)     // 7813 edges per block
#define ROUNDS1 ((EPB + 255) / 256)             // 31 staging rounds
#define BCAP 3776                               // bucket window; mean 3413, +6.2 sigma
#define RING2_D 96                              // L2 ring depth per bucket
#define CHUNK2 32                               // L2 flush granularity = 256 B

static __device__ __forceinline__ unsigned short f32_to_bf16_rne(float f) {
    unsigned u = __float_as_uint(f);
    u += 0x7FFFu + ((u >> 16) & 1u);
    return (unsigned short)(u >> 16);
}
static __device__ __forceinline__ float bf16_to_f32(unsigned short h) {
    return __uint_as_float(((unsigned)h) << 16);
}

// ---------- concat + quantize to bf16 (float4 -> ushort4) ----------
__global__ __launch_bounds__(256) void concat_bf16_kernel(const float* __restrict__ u,
                                                          const float* __restrict__ it,
                                                          unsigned short* __restrict__ out) {
    long i4 = (long)blockIdx.x * 256 + threadIdx.x;
    const long usz4 = (long)USER_NUM * EMB / 4;
    const long tot4 = (long)NN * EMB / 4;
    if (i4 >= tot4) return;
    const float4* src = (i4 < usz4) ? (const float4*)u : (const float4*)it;
    long j = (i4 < usz4) ? i4 : (i4 - usz4);
    float4 v = src[j];
    ushort4 o;
    o.x = f32_to_bf16_rne(v.x); o.y = f32_to_bf16_rne(v.y);
    o.z = f32_to_bf16_rne(v.z); o.w = f32_to_bf16_rne(v.w);
    ((ushort4*)out)[i4] = o;
}

// ================= NEW PATH: two-level multisplit =================
// L1: stream edges, bin into 293 super-bins via LDS rings, flush 64B-aligned
// 8-edge chunks (1 global atomic per chunk instead of per edge).
__global__ __launch_bounds__(256) void l1_multisplit(const int* __restrict__ rows,
                                                     const int* __restrict__ cols,
                                                     const float* __restrict__ vals,
                                                     int* __restrict__ sfill,
                                                     uint2* __restrict__ sbuf) {
    __shared__ uint2 ring[NSB * RING_D];        // 56.3 KB
    __shared__ int   cnt[NSB];
    __shared__ int   dbin[NSB], dgs[NSB], dn[NSB];
    __shared__ int   dpref[NSB + 1];
    __shared__ int   dcount, dtotal;

    const int tid   = threadIdx.x;
    const int start = blockIdx.x * EPB;
    const int end   = (start + EPB < N_EDGES) ? (start + EPB) : N_EDGES;

    for (int b = tid; b < NSB; b += 256) cnt[b] = 0;
    __syncthreads();

    int e = start + tid;
    int pr = -1; unsigned pc = 0; unsigned pv = 0;
    if (e < end) { pr = rows[e]; pc = (unsigned)cols[e]; pv = __float_as_uint(vals[e]); }

    for (int round = 0; round <= ROUNDS1; ++round) {
        const bool flushAll = (round == ROUNDS1);
        if (!flushAll) {
            int r = pr; unsigned c = pc, v = pv;
            int e2 = e + 256;                    // prefetch next round
            pr = -1;
            if (e2 < end) { pr = rows[e2]; pc = (unsigned)cols[e2]; pv = __float_as_uint(vals[e2]); }
            e = e2;
            if (r >= 0) {
                int b = r >> SBSHIFT;
                int rank = atomicAdd(&cnt[b], 1);
                if (rank < RING_D) {
                    uint2 pk;
                    pk.x = ((unsigned)r & (SBROWS - 1)) | (c << SBSHIFT);
                    pk.y = v;
                    ring[b * RING_D + rank] = pk;
                }
            }
        }
        __syncthreads();
        if (tid == 0) dcount = 0;
        __syncthreads();
        // descriptor generation: one global atomic per flushed chunk-group
        for (int b = tid; b < NSB; b += 256) {
            int c = cnt[b]; if (c > RING_D) c = RING_D;
            int nfl = flushAll ? c : (c & ~(CHUNK1 - 1));
            if (nfl > 0) {
                int gs = atomicAdd(&sfill[b], nfl);
                int di = atomicAdd(&dcount, 1);
                dbin[di] = b; dgs[di] = gs; dn[di] = nfl;
            }
        }
        __syncthreads();
        if (tid == 0) {
            int run = 0;
            for (int i = 0; i < dcount; ++i) { dpref[i] = run; run += dn[i]; }
            dpref[dcount] = run; dtotal = run;
        }
        __syncthreads();
        // cooperative copy: consecutive threads -> consecutive slots (full lines)
        for (int j = tid; j < dtotal; j += 256) {
            int di = 0;
            while (dpref[di + 1] <= j) ++di;
            int off  = j - dpref[di];
            int b    = dbin[di];
            int gpos = dgs[di] + off;
            if (gpos < SCAP)
                sbuf[(size_t)b * SCAP + gpos] = ring[b * RING_D + off];
        }
        __syncthreads();
        // move residual (<CHUNK1) to ring front; disjoint since nfl>=8>res
        for (int b = tid; b < NSB; b += 256) {
            int c = cnt[b]; if (c > RING_D) c = RING_D;
            int nfl = flushAll ? c : (c & ~(CHUNK1 - 1));
            int res = c - nfl;
            for (int i = 0; i < res; ++i)
                ring[b * RING_D + i] = ring[b * RING_D + nfl + i];
            cnt[b] = res;
        }
        __syncthreads();
    }
}

// L2: one block per super-bin (single owner of its 8 bucket frontiers ->
// zero global atomics), splits into 64-row bucket windows, 256B chunk flushes.
__global__ __launch_bounds__(256) void l2_split(const int* __restrict__ sfill,
                                                const uint2* __restrict__ sbuf,
                                                int* __restrict__ bfill,
                                                uint2* __restrict__ bbuf2) {
    __shared__ uint2 ring[8 * RING2_D];          // 6 KB
    __shared__ int cnt8[8], goff[8], dn8[8], dgs8[8];

    const int s   = blockIdx.x;
    const int tid = threadIdx.x;
    int total = sfill[s]; if (total > SCAP) total = SCAP;
    const uint2* src = sbuf + (size_t)s * SCAP;

    if (tid < 8) { cnt8[tid] = 0; goff[tid] = 0; }
    __syncthreads();

    const int nrounds = (total + 255) / 256;
    for (int round = 0; round <= nrounds; ++round) {
        const bool flushAll = (round == nrounds);
        if (!flushAll) {
            int i = round * 256 + tid;
            if (i < total) {
                uint2 pk = src[i];
                int bl = (int)((pk.x & (SBROWS - 1)) >> BSHIFT);   // 0..7
                int rank = atomicAdd(&cnt8[bl], 1);
                if (rank < RING2_D) ring[bl * RING2_D + rank] = pk;
            }
        }
        __syncthreads();
        if (tid < 8) {
            int c = cnt8[tid]; if (c > RING2_D) c = RING2_D;
            int nfl = flushAll ? c : (c & ~(CHUNK2 - 1));
            dn8[tid] = nfl; dgs8[tid] = goff[tid];
            goff[tid] += nfl;
        }
        __syncthreads();
        {
            int bl = tid >> 5, i = tid & 31;
            int nfl = dn8[bl];
            int gbase = dgs8[bl];
            size_t obase = (size_t)(s * 8 + bl) * BCAP;
            for (int j = i; j < nfl; j += 32) {
                int gpos = gbase + j;
                if (gpos < BCAP) {
                    uint2 pk = ring[bl * RING2_D + j];
                    unsigned rl9 = pk.x & (SBROWS - 1);
                    unsigned col = pk.x >> SBSHIFT;
                    uint2 o;
                    o.x = (rl9 & (BROWS - 1)) | (col << BSHIFT);
                    o.y = pk.y;
                    bbuf2[obase + gpos] = o;
                }
            }
        }
        __syncthreads();
        {
            int bl = tid >> 5, i = tid & 31;
            int c = cnt8[bl]; if (c > RING2_D) c = RING2_D;
            int nfl = dn8[bl];
            int res = c - nfl;                   // res <= 31 < nfl when nfl>0: disjoint
            if (nfl > 0 && i < res)
                ring[bl * RING2_D + i] = ring[bl * RING2_D + nfl + i];
            if (i == 0) cnt8[bl] = res;
        }
        __syncthreads();
    }
    if (tid < 8) {
        int b = s * 8 + tid;
        if (b < NB) bfill[b] = (goff[tid] < BCAP) ? goff[tid] : BCAP;
    }
}

// per-bucket LDS counting sort over a single contiguous segment, in-place
__global__ __launch_bounds__(256) void bucket_sort_single(const int* __restrict__ bfill,
                                                          uint2* __restrict__ bbuf2,
                                                          int* __restrict__ row_start,
                                                          int* __restrict__ row_cnt) {
    __shared__ uint2 buf[BCAP];                  // 30.2 KB
    __shared__ int h[BROWS], pref[BROWS], fill[BROWS];
    int b = blockIdx.x, tid = threadIdx.x;
    int total = bfill[b]; if (total > BCAP) total = BCAP;
    uint2* win = bbuf2 + (size_t)b * BCAP;
    if (tid < BROWS) { h[tid] = 0; fill[tid] = 0; }
    __syncthreads();
    for (int i = tid; i < total; i += 256) buf[i] = win[i];
    __syncthreads();
    for (int i = tid; i < total; i += 256) atomicAdd(&h[buf[i].x & (BROWS - 1)], 1);
    __syncthreads();
    if (tid == 0) {
        int run = 0;
        #pragma unroll
        for (int r = 0; r < BROWS; ++r) { pref[r] = run; run += h[r]; }
    }
    __syncthreads();
    for (int i = tid; i < total; i += 256) {
        unsigned m = buf[i].x;
        int rl = (int)(m & (BROWS - 1));
        int pos = pref[rl] + atomicAdd(&fill[rl], 1);
        uint2 pk; pk.x = m >> BSHIFT; pk.y = buf[i].y;
        win[pos] = pk;
    }
    if (tid < BROWS) {
        int row = b * BROWS + tid;
        if (row < NN) { row_start[row] = b * BCAP + pref[tid]; row_cnt[row] = h[tid]; }
    }
}

// ================= OLD PATH (verbatim fallback) =================
__global__ __launch_bounds__(256) void bucket_scatter_fixed(const int* __restrict__ rows,
                                                            const int* __restrict__ cols,
                                                            const float* __restrict__ vals,
                                                            int* __restrict__ bfill,
                                                            uint2* __restrict__ bbuf) {
    int e = blockIdx.x * 256 + threadIdx.x;
    if (e >= N_EDGES) return;
    int sub = blockIdx.x & (NSUB - 1);
    int r = rows[e];
    int b = r >> BSHIFT;
    int pos = atomicAdd(&bfill[b * NSUB + sub], 1);
    if (pos < CAPS) {
        uint2 pk;
        pk.x = (unsigned)(r & (BROWS - 1)) | ((unsigned)cols[e] << BSHIFT);
        pk.y = __float_as_uint(vals[e]);
        bbuf[(size_t)b * WIN + sub * CAPS + pos] = pk;
    }
}

__global__ __launch_bounds__(256) void bucket_sort_fixed(const int* __restrict__ bfill,
                                                         uint2* __restrict__ bbuf,
                                                         int* __restrict__ row_start,
                                                         int* __restrict__ row_cnt) {
    __shared__ uint2 buf[CAP];
    __shared__ int scnt[NSUB], soff[NSUB];
    __shared__ int h[BROWS], pref[BROWS], fill[BROWS];
    int b = blockIdx.x;
    int tid = threadIdx.x;
    if (tid < NSUB) {
        int c = bfill[b * NSUB + tid];
        scnt[tid] = (c < CAPS) ? c : CAPS;
    }
    if (tid < BROWS) { h[tid] = 0; fill[tid] = 0; }
    __syncthreads();
    if (tid == 0) {
        int run = 0;
        #pragma unroll
        for (int s = 0; s < NSUB; ++s) { soff[s] = run; run += scnt[s]; }
    }
    __syncthreads();
    int total = soff[NSUB - 1] + scnt[NSUB - 1];
    if (total > CAP) total = CAP;
    for (int s = 0; s < NSUB; ++s) {
        int c = scnt[s], off = soff[s];
        const uint2* src = bbuf + (size_t)b * WIN + s * CAPS;
        for (int i = tid; i < c; i += 256)
            if (off + i < CAP) buf[off + i] = src[i];
    }
    __syncthreads();
    for (int i = tid; i < total; i += 256) atomicAdd(&h[buf[i].x & (BROWS - 1)], 1);
    __syncthreads();
    if (tid == 0) {
        int run = 0;
        #pragma unroll
        for (int r = 0; r < BROWS; ++r) { pref[r] = run; run += h[r]; }
    }
    __syncthreads();
    uint2* dst = bbuf + (size_t)b * WIN;
    for (int i = tid; i < total; i += 256) {
        unsigned m = buf[i].x;
        int rl = (int)(m & (BROWS - 1));
        int pos = pref[rl] + atomicAdd(&fill[rl], 1);
        uint2 pk;
        pk.x = m >> BSHIFT;
        pk.y = buf[i].y;
        dst[pos] = pk;
    }
    if (tid < BROWS) {
        int row = b * BROWS + tid;
        if (row < NN) { row_start[row] = b * WIN + pref[tid]; row_cnt[row] = h[tid]; }
    }
}

// ---------- fused CSR SpMM (wave per row, reg accumulation, bf16 gather) ----------
__global__ __launch_bounds__(256) void spmm_csr_fused(const int* __restrict__ row_start,
                                                      const int* __restrict__ row_cnt,
                                                      const uint2* __restrict__ csr,
                                                      const unsigned short* __restrict__ x,
                                                      const float* __restrict__ noise_k,
                                                      unsigned short* __restrict__ ego_out,
                                                      float* __restrict__ acc,
                                                      int mode) {
    int row = (blockIdx.x * 256 + threadIdx.x) >> 6;
    int lane = threadIdx.x & 63;
    if (row >= NN) return;
    int s = row_start[row];
    int end = s + row_cnt[row];

    float a0 = 0.f, a1 = 0.f, a2 = 0.f, a3 = 0.f;
    float a4 = 0.f, a5 = 0.f, a6 = 0.f, a7 = 0.f;
    int e = s;
    for (; e + 8 <= end; e += 8) {
        uint2 p0 = csr[e],     p1 = csr[e + 1], p2 = csr[e + 2], p3 = csr[e + 3];
        uint2 p4 = csr[e + 4], p5 = csr[e + 5], p6 = csr[e + 6], p7 = csr[e + 7];
        a0 += __uint_as_float(p0.y) * bf16_to_f32(x[(size_t)p0.x * EMB + lane]);
        a1 += __uint_as_float(p1.y) * bf16_to_f32(x[(size_t)p1.x * EMB + lane]);
        a2 += __uint_as_float(p2.y) * bf16_to_f32(x[(size_t)p2.x * EMB + lane]);
        a3 += __uint_as_float(p3.y) * bf16_to_f32(x[(size_t)p3.x * EMB + lane]);
        a4 += __uint_as_float(p4.y) * bf16_to_f32(x[(size_t)p4.x * EMB + lane]);
        a5 += __uint_as_float(p5.y) * bf16_to_f32(x[(size_t)p5.x * EMB + lane]);
        a6 += __uint_as_float(p6.y) * bf16_to_f32(x[(size_t)p6.x * EMB + lane]);
        a7 += __uint_as_float(p7.y) * bf16_to_f32(x[(size_t)p7.x * EMB + lane]);
    }
    for (; e < end; ++e) {
        uint2 p = csr[e];
        a0 += __uint_as_float(p.y) * bf16_to_f32(x[(size_t)p.x * EMB + lane]);
    }
    float a = ((a0 + a1) + (a2 + a3)) + ((a4 + a5) + (a6 + a7));

    size_t idx = (size_t)row * EMB + lane;
    float nv = noise_k[idx];
    float ss = nv * nv;
    #pragma unroll
    for (int off = 32; off >= 1; off >>= 1) ss += __shfl_xor(ss, off, 64);
    float nrm = fmaxf(sqrtf(ss), 1e-12f);
    float sgn = (a > 0.0f) ? 1.0f : ((a < 0.0f) ? -1.0f : 0.0f);
    float e1 = a + sgn * (nv / nrm) * EPS_C;

    ego_out[idx] = f32_to_bf16_rne(e1);
    if (mode == 0)      acc[idx] = e1;
    else if (mode == 1) acc[idx] += e1;
    else                acc[idx] = (acc[idx] + e1) * (1.0f / 3.0f);
}

// ---------- fallback: fp32 atomic path (needs 76.8 MB ws) ----------
__global__ __launch_bounds__(256) void concat_f32_kernel(const float* __restrict__ u,
                                                         const float* __restrict__ it,
                                                         float* __restrict__ out) {
    long i = (long)blockIdx.x * 256 + threadIdx.x;
    const long usz = (long)USER_NUM * EMB;
    const long tot = (long)NN * EMB;
    if (i >= tot) return;
    out[i] = (i < usz) ? u[i] : it[i - usz];
}

__global__ __launch_bounds__(256) void spmm_atomic_kernel(const int* __restrict__ rows,
                                                          const int* __restrict__ cols,
                                                          const float* __restrict__ vals,
                                                          const float* __restrict__ x,
                                                          float* __restrict__ y) {
    long t = (long)blockIdx.x * 256 + threadIdx.x;
    int e = (int)(t >> 6);
    int lane = (int)(t & 63);
    if (e >= N_EDGES) return;
    atomicAdd(&y[(long)rows[e] * EMB + lane], vals[e] * x[(long)cols[e] * EMB + lane]);
}

__global__ __launch_bounds__(256) void noise_acc_kernel(float* __restrict__ ego,
                                                        const float* __restrict__ noise_k,
                                                        float* __restrict__ acc,
                                                        int mode) {
    long t = (long)blockIdx.x * 256 + threadIdx.x;
    int node = (int)(t >> 6);
    int lane = (int)(t & 63);
    if (node >= NN) return;
    long idx = (long)node * EMB + lane;
    float nv = noise_k[idx];
    float s = nv * nv;
    #pragma unroll
    for (int off = 32; off >= 1; off >>= 1) s += __shfl_xor(s, off, 64);
    float nrm = fmaxf(sqrtf(s), 1e-12f);
    float e0 = ego[idx];
    float sgn = (e0 > 0.0f) ? 1.0f : ((e0 < 0.0f) ? -1.0f : 0.0f);
    float e1 = e0 + sgn * (nv / nrm) * EPS_C;
    ego[idx] = e1;
    if (mode == 0)      acc[idx] = e1;
    else if (mode == 1) acc[idx] += e1;
    else                acc[idx] = (acc[idx] + e1) * (1.0f / 3.0f);
}

extern "C" void kernel_launch(void* const* d_in, const int* in_sizes, int n_in,
                              void* d_out, int out_size, void* d_ws, size_t ws_size,
                              hipStream_t stream) {
    const float* user_emb   = (const float*)d_in[0];
    const float* item_emb   = (const float*)d_in[1];
    const float* user_proto = (const float*)d_in[2];
    const float* item_proto = (const float*)d_in[3];
    const int*   rows       = (const int*)d_in[4];
    const int*   cols       = (const int*)d_in[5];
    const float* vals       = (const float*)d_in[6];
    const float* noise      = (const float*)d_in[7];
    float* out = (float*)d_out;

    const size_t EGO_BF = ((size_t)NN * EMB * sizeof(unsigned short) + 255) & ~(size_t)255;
    const size_t NARR   = ((size_t)NN * sizeof(int) + 255) & ~(size_t)255;

    // ---- new path layout (~176.5 MB) ----
    const size_t SBUF_SZ  = (size_t)NSB * SCAP * sizeof(uint2);      // 66.0 MB
    const size_t BBUF2_SZ = (size_t)NB * BCAP * sizeof(uint2);       // 70.8 MB
    const size_t SFILL_SZ = ((size_t)NSB * sizeof(int) + 255) & ~(size_t)255;
    const size_t BFILL2_SZ= ((size_t)NB * sizeof(int) + 255) & ~(size_t)255;
    const size_t required_new = 2 * EGO_BF + SBUF_SZ + BBUF2_SZ + 2 * NARR + SFILL_SZ + BFILL2_SZ;

    // ---- old path layout (~131 MB) ----
    const size_t BBUF   = (size_t)NB * WIN * sizeof(uint2);
    const size_t FARR   = ((size_t)NB * NSUB * sizeof(int) + 255) & ~(size_t)255;
    const size_t required_old = 2 * EGO_BF + BBUF + 2 * NARR + FARR;

    float* acc = out;
    const int elemTotal  = NN * EMB;
    const int elemBlocks = (elemTotal + 255) / 256;
    const int vecBlocks  = (elemTotal / 4 + 255) / 256;
    const int edgeBlocks = (N_EDGES + 255) / 256;
    const int rowWaveBlocks = (NN + 3) / 4;

    if (ws_size >= required_new) {
        char* p = (char*)d_ws;
        unsigned short* egoA = (unsigned short*)p;  p += EGO_BF;
        unsigned short* egoB = (unsigned short*)p;  p += EGO_BF;
        uint2* sbuf          = (uint2*)p;           p += SBUF_SZ;
        uint2* bbuf2         = (uint2*)p;           p += BBUF2_SZ;
        int* row_start       = (int*)p;             p += NARR;
        int* row_cnt         = (int*)p;             p += NARR;
        int* sfill           = (int*)p;             p += SFILL_SZ;
        int* bfill2          = (int*)p;             p += BFILL2_SZ;

        concat_bf16_kernel<<<vecBlocks, 256, 0, stream>>>(user_emb, item_emb, egoA);
        hipMemsetAsync(sfill, 0, (size_t)NSB * sizeof(int), stream);
        l1_multisplit<<<GRID1, 256, 0, stream>>>(rows, cols, vals, sfill, sbuf);
        l2_split<<<NSB, 256, 0, stream>>>(sfill, sbuf, bfill2, bbuf2);
        bucket_sort_single<<<NB, 256, 0, stream>>>(bfill2, bbuf2, row_start, row_cnt);

        unsigned short* cur = egoA;
        unsigned short* nxt = egoB;
        for (int k = 0; k < 3; ++k) {
            int mode = (k == 0) ? 0 : ((k == 2) ? 2 : 1);
            spmm_csr_fused<<<rowWaveBlocks, 256, 0, stream>>>(
                row_start, row_cnt, bbuf2, cur,
                noise + (size_t)k * NN * EMB, nxt, acc, mode);
            unsigned short* t = cur; cur = nxt; nxt = t;
        }
    } else if (ws_size >= required_old) {
        char* p = (char*)d_ws;
        unsigned short* egoA = (unsigned short*)p;  p += EGO_BF;
        unsigned short* egoB = (unsigned short*)p;  p += EGO_BF;
        uint2* bbuf          = (uint2*)p;           p += BBUF;
        int* row_start       = (int*)p;             p += NARR;
        int* row_cnt         = (int*)p;             p += NARR;
        int* bfill           = (int*)p;             p += FARR;

        concat_bf16_kernel<<<vecBlocks, 256, 0, stream>>>(user_emb, item_emb, egoA);
        hipMemsetAsync(bfill, 0, (size_t)NB * NSUB * sizeof(int), stream);
        bucket_scatter_fixed<<<edgeBlocks, 256, 0, stream>>>(rows, cols, vals, bfill, bbuf);
        bucket_sort_fixed<<<NB, 256, 0, stream>>>(bfill, bbuf, row_start, row_cnt);

        unsigned short* cur = egoA;
        unsigned short* nxt = egoB;
        for (int k = 0; k < 3; ++k) {
            int mode = (k == 0) ? 0 : ((k == 2) ? 2 : 1);
            spmm_csr_fused<<<rowWaveBlocks, 256, 0, stream>>>(
                row_start, row_cnt, bbuf, cur,
                noise + (size_t)k * NN * EMB, nxt, acc, mode);
            unsigned short* t = cur; cur = nxt; nxt = t;
        }
    } else {
        const size_t EGO_SZ = (size_t)NN * EMB * sizeof(float);
        float* fA = (float*)d_ws;
        float* fB = (float*)((char*)d_ws + EGO_SZ);
        concat_f32_kernel<<<elemBlocks, 256, 0, stream>>>(user_emb, item_emb, fA);
        float* cur = fA; float* nxt = fB;
        for (int k = 0; k < 3; ++k) {
            hipMemsetAsync(nxt, 0, EGO_SZ, stream);
            spmm_atomic_kernel<<<N_EDGES / 4, 256, 0, stream>>>(rows, cols, vals, cur, nxt);
            int mode = (k == 0) ? 0 : ((k == 2) ? 2 : 1);
            noise_acc_kernel<<<elemBlocks, 256, 0, stream>>>(
                nxt, noise + (size_t)k * NN * EMB, acc, mode);
            float* t = cur; cur = nxt; nxt = t;
        }
    }

    hipMemcpyAsync(out + (size_t)NN * EMB, user_proto,
                   (size_t)PROTO * EMB * sizeof(float), hipMemcpyDeviceToDevice, stream);
    hipMemcpyAsync(out + (size_t)NN * EMB + (size_t)PROTO * EMB, item_proto,
                   (size_t)PROTO * EMB * sizeof(float), hipMemcpyDeviceToDevice, stream);
}

// Round 2
// 1144.735 us; speedup vs baseline: 1.3783x; 1.3783x over previous
//
#include <hip/hip_runtime.h>

#define USER_NUM 100000
#define ITEM_NUM 50000
#define NN (USER_NUM + ITEM_NUM)
#define EMB 64
#define N_EDGES 8000000
#define EPS_C 0.1f
#define PROTO 4000

// ---------------- old-path params (kept verbatim as ws fallback) ----------------
#define BSHIFT 6
#define BROWS 64                                // rows per bucket
#define NB ((NN + BROWS - 1) / BROWS)           // 2344 buckets
#define NSUB 8
#define CAPS 608
#define WIN (NSUB * CAPS)
#define CAP 4608

// ---------------- hierarchical split params ----------------
#define SBSHIFT 9
#define SBROWS 512                              // rows per super-bin
#define NSB ((NN + SBROWS - 1) / SBROWS)        // 293 super-bins
#define SCAP 28160                              // slots/super-bin; mean 27304, +5.2 sigma
#define SF_STRIDE 16                            // pad sfill counters to one 64B line each
#define BCAP 3776                               // bucket window; mean 3413, +6.2 sigma
#define RING2_D 96                              // L2 ring depth per bucket
#define CHUNK2 32                               // L2 flush granularity = 256 B
// chunk-sort scatter
#define CHS 8192                                // edges per block chunk (LDS-resident)
#define NCH ((N_EDGES + CHS - 1) / CHS)         // 977 blocks

static __device__ __forceinline__ unsigned short f32_to_bf16_rne(float f) {
    unsigned u = __float_as_uint(f);
    u += 0x7FFFu + ((u >> 16) & 1u);
    return (unsigned short)(u >> 16);
}
static __device__ __forceinline__ float bf16_to_f32(unsigned short h) {
    return __uint_as_float(((unsigned)h) << 16);
}

// ---------- concat + quantize to bf16 (float4 -> ushort4) ----------
__global__ __launch_bounds__(256) void concat_bf16_kernel(const float* __restrict__ u,
                                                          const float* __restrict__ it,
                                                          unsigned short* __restrict__ out) {
    long i4 = (long)blockIdx.x * 256 + threadIdx.x;
    const long usz4 = (long)USER_NUM * EMB / 4;
    const long tot4 = (long)NN * EMB / 4;
    if (i4 >= tot4) return;
    const float4* src = (i4 < usz4) ? (const float4*)u : (const float4*)it;
    long j = (i4 < usz4) ? i4 : (i4 - usz4);
    float4 v = src[j];
    ushort4 o;
    o.x = f32_to_bf16_rne(v.x); o.y = f32_to_bf16_rne(v.y);
    o.z = f32_to_bf16_rne(v.z); o.w = f32_to_bf16_rne(v.w);
    ((ushort4*)out)[i4] = o;
}

// ================= chunk counting-sort scatter (single shot per block) =================
// Per block: LDS counting sort of an 8192-edge chunk by super-bin, one padded global
// atomic per (block,bin) to reserve space, then contiguous full-line writes out.
__global__ __launch_bounds__(256) void chunk_sort_scatter(const int* __restrict__ rows,
                                                          const int* __restrict__ cols,
                                                          const float* __restrict__ vals,
                                                          int* __restrict__ sfill,
                                                          uint2* __restrict__ sbuf) {
    __shared__ unsigned skey[CHS];              // 32 KB
    __shared__ unsigned sval[CHS];              // 32 KB
    __shared__ int hist[NSB];
    __shared__ int pref[NSB + 1];
    __shared__ int gbase[NSB];
    __shared__ int fill[NSB];

    const int tid   = threadIdx.x;
    const int start = blockIdx.x * CHS;
    const int n     = (start + CHS <= N_EDGES) ? CHS : (N_EDGES - start);
    const int n4    = n >> 2;                   // all chunk sizes are multiples of 4

    for (int b = tid; b < NSB; b += 256) { hist[b] = 0; fill[b] = 0; }
    __syncthreads();

    // phase 1: histogram (vectorized row read)
    const int4* rows4 = (const int4*)(rows + start);
    for (int i = tid; i < n4; i += 256) {
        int4 r = rows4[i];
        atomicAdd(&hist[r.x >> SBSHIFT], 1);
        atomicAdd(&hist[r.y >> SBSHIFT], 1);
        atomicAdd(&hist[r.z >> SBSHIFT], 1);
        atomicAdd(&hist[r.w >> SBSHIFT], 1);
    }
    __syncthreads();

    // exclusive prefix scan over 293 bins: wave-0 shuffle scan (no serial LDS chain)
    if (tid < 64) {
        int carry = 0;
        #pragma unroll
        for (int g = 0; g < (NSB + 63) / 64; ++g) {
            int idx = g * 64 + tid;
            int h = (idx < NSB) ? hist[idx] : 0;
            int v = h;
            #pragma unroll
            for (int off = 1; off < 64; off <<= 1) {
                int t = __shfl_up(v, off, 64);
                if (tid >= off) v += t;
            }
            if (idx < NSB) pref[idx] = carry + v - h;
            carry += __shfl(v, 63, 64);
        }
        if (tid == 0) pref[NSB] = carry;
    }
    __syncthreads();

    // reserve global space: one padded-line atomic per non-empty (block,bin)
    for (int b = tid; b < NSB; b += 256)
        gbase[b] = hist[b] ? atomicAdd(&sfill[b * SF_STRIDE], hist[b]) : 0;

    // phase 2: scatter edges into LDS at sorted positions
    const int4*   cols4 = (const int4*)(cols + start);
    const float4* vals4 = (const float4*)(vals + start);
    for (int i = tid; i < n4; i += 256) {
        int4   r = rows4[i];
        int4   c = cols4[i];
        float4 v = vals4[i];
        {
            int b = r.x >> SBSHIFT; int p = pref[b] + atomicAdd(&fill[b], 1);
            skey[p] = ((unsigned)r.x & (SBROWS - 1)) | ((unsigned)c.x << SBSHIFT);
            sval[p] = __float_as_uint(v.x);
        }
        {
            int b = r.y >> SBSHIFT; int p = pref[b] + atomicAdd(&fill[b], 1);
            skey[p] = ((unsigned)r.y & (SBROWS - 1)) | ((unsigned)c.y << SBSHIFT);
            sval[p] = __float_as_uint(v.y);
        }
        {
            int b = r.z >> SBSHIFT; int p = pref[b] + atomicAdd(&fill[b], 1);
            skey[p] = ((unsigned)r.z & (SBROWS - 1)) | ((unsigned)c.z << SBSHIFT);
            sval[p] = __float_as_uint(v.z);
        }
        {
            int b = r.w >> SBSHIFT; int p = pref[b] + atomicAdd(&fill[b], 1);
            skey[p] = ((unsigned)r.w & (SBROWS - 1)) | ((unsigned)c.w << SBSHIFT);
            sval[p] = __float_as_uint(v.w);
        }
    }
    __syncthreads();

    // phase 3: stream sorted chunk out; consecutive threads -> consecutive slots
    for (int j = tid; j < n; j += 256) {
        int lo = 0, hi = NSB;                   // largest b with pref[b] <= j
        while (hi - lo > 1) {
            int mid = (lo + hi) >> 1;
            if (pref[mid] <= j) lo = mid; else hi = mid;
        }
        int gpos = gbase[lo] + (j - pref[lo]);
        if (gpos < SCAP) {
            uint2 pk; pk.x = skey[j]; pk.y = sval[j];
            sbuf[(size_t)lo * SCAP + gpos] = pk;
        }
    }
}

// L2: one block per super-bin (single owner of its 8 bucket frontiers ->
// zero global atomics), splits into 64-row bucket windows, 256B chunk flushes.
__global__ __launch_bounds__(256) void l2_split(const int* __restrict__ sfill,
                                                const uint2* __restrict__ sbuf,
                                                int* __restrict__ bfill,
                                                uint2* __restrict__ bbuf2) {
    __shared__ uint2 ring[8 * RING2_D];          // 6 KB
    __shared__ int cnt8[8], goff[8], dn8[8], dgs8[8];

    const int s   = blockIdx.x;
    const int tid = threadIdx.x;
    int total = sfill[s * SF_STRIDE]; if (total > SCAP) total = SCAP;
    const uint2* src = sbuf + (size_t)s * SCAP;

    if (tid < 8) { cnt8[tid] = 0; goff[tid] = 0; }
    __syncthreads();

    const int nrounds = (total + 255) / 256;
    for (int round = 0; round <= nrounds; ++round) {
        const bool flushAll = (round == nrounds);
        if (!flushAll) {
            int i = round * 256 + tid;
            if (i < total) {
                uint2 pk = src[i];
                int bl = (int)((pk.x & (SBROWS - 1)) >> BSHIFT);   // 0..7
                int rank = atomicAdd(&cnt8[bl], 1);
                if (rank < RING2_D) ring[bl * RING2_D + rank] = pk;
            }
        }
        __syncthreads();
        if (tid < 8) {
            int c = cnt8[tid]; if (c > RING2_D) c = RING2_D;
            int nfl = flushAll ? c : (c & ~(CHUNK2 - 1));
            dn8[tid] = nfl; dgs8[tid] = goff[tid];
            goff[tid] += nfl;
        }
        __syncthreads();
        {
            int bl = tid >> 5, i = tid & 31;
            int nfl = dn8[bl];
            int gbase = dgs8[bl];
            size_t obase = (size_t)(s * 8 + bl) * BCAP;
            for (int j = i; j < nfl; j += 32) {
                int gpos = gbase + j;
                if (gpos < BCAP) {
                    uint2 pk = ring[bl * RING2_D + j];
                    unsigned rl9 = pk.x & (SBROWS - 1);
                    unsigned col = pk.x >> SBSHIFT;
                    uint2 o;
                    o.x = (rl9 & (BROWS - 1)) | (col << BSHIFT);
                    o.y = pk.y;
                    bbuf2[obase + gpos] = o;
                }
            }
        }
        __syncthreads();
        {
            int bl = tid >> 5, i = tid & 31;
            int c = cnt8[bl]; if (c > RING2_D) c = RING2_D;
            int nfl = dn8[bl];
            int res = c - nfl;                   // res <= 31 < nfl when nfl>0: disjoint
            if (nfl > 0 && i < res)
                ring[bl * RING2_D + i] = ring[bl * RING2_D + nfl + i];
            if (i == 0) cnt8[bl] = res;
        }
        __syncthreads();
    }
    if (tid < 8) {
        int b = s * 8 + tid;
        if (b < NB) bfill[b] = (goff[tid] < BCAP) ? goff[tid] : BCAP;
    }
}

// per-bucket LDS counting sort over a single contiguous segment, in-place
__global__ __launch_bounds__(256) void bucket_sort_single(const int* __restrict__ bfill,
                                                          uint2* __restrict__ bbuf2,
                                                          int* __restrict__ row_start,
                                                          int* __restrict__ row_cnt) {
    __shared__ uint2 buf[BCAP];                  // 30.2 KB
    __shared__ int h[BROWS], pref[BROWS], fill[BROWS];
    int b = blockIdx.x, tid = threadIdx.x;
    int total = bfill[b]; if (total > BCAP) total = BCAP;
    uint2* win = bbuf2 + (size_t)b * BCAP;
    if (tid < BROWS) { h[tid] = 0; fill[tid] = 0; }
    __syncthreads();
    for (int i = tid; i < total; i += 256) buf[i] = win[i];
    __syncthreads();
    for (int i = tid; i < total; i += 256) atomicAdd(&h[buf[i].x & (BROWS - 1)], 1);
    __syncthreads();
    if (tid == 0) {
        int run = 0;
        #pragma unroll
        for (int r = 0; r < BROWS; ++r) { pref[r] = run; run += h[r]; }
    }
    __syncthreads();
    for (int i = tid; i < total; i += 256) {
        unsigned m = buf[i].x;
        int rl = (int)(m & (BROWS - 1));
        int pos = pref[rl] + atomicAdd(&fill[rl], 1);
        uint2 pk; pk.x = m >> BSHIFT; pk.y = buf[i].y;
        win[pos] = pk;
    }
    if (tid < BROWS) {
        int row = b * BROWS + tid;
        if (row < NN) { row_start[row] = b * BCAP + pref[tid]; row_cnt[row] = h[tid]; }
    }
}

// ================= OLD PATH (verbatim fallback) =================
__global__ __launch_bounds__(256) void bucket_scatter_fixed(const int* __restrict__ rows,
                                                            const int* __restrict__ cols,
                                                            const float* __restrict__ vals,
                                                            int* __restrict__ bfill,
                                                            uint2* __restrict__ bbuf) {
    int e = blockIdx.x * 256 + threadIdx.x;
    if (e >= N_EDGES) return;
    int sub = blockIdx.x & (NSUB - 1);
    int r = rows[e];
    int b = r >> BSHIFT;
    int pos = atomicAdd(&bfill[b * NSUB + sub], 1);
    if (pos < CAPS) {
        uint2 pk;
        pk.x = (unsigned)(r & (BROWS - 1)) | ((unsigned)cols[e] << BSHIFT);
        pk.y = __float_as_uint(vals[e]);
        bbuf[(size_t)b * WIN + sub * CAPS + pos] = pk;
    }
}

__global__ __launch_bounds__(256) void bucket_sort_fixed(const int* __restrict__ bfill,
                                                         uint2* __restrict__ bbuf,
                                                         int* __restrict__ row_start,
                                                         int* __restrict__ row_cnt) {
    __shared__ uint2 buf[CAP];
    __shared__ int scnt[NSUB], soff[NSUB];
    __shared__ int h[BROWS], pref[BROWS], fill[BROWS];
    int b = blockIdx.x;
    int tid = threadIdx.x;
    if (tid < NSUB) {
        int c = bfill[b * NSUB + tid];
        scnt[tid] = (c < CAPS) ? c : CAPS;
    }
    if (tid < BROWS) { h[tid] = 0; fill[tid] = 0; }
    __syncthreads();
    if (tid == 0) {
        int run = 0;
        #pragma unroll
        for (int s = 0; s < NSUB; ++s) { soff[s] = run; run += scnt[s]; }
    }
    __syncthreads();
    int total = soff[NSUB - 1] + scnt[NSUB - 1];
    if (total > CAP) total = CAP;
    for (int s = 0; s < NSUB; ++s) {
        int c = scnt[s], off = soff[s];
        const uint2* src = bbuf + (size_t)b * WIN + s * CAPS;
        for (int i = tid; i < c; i += 256)
            if (off + i < CAP) buf[off + i] = src[i];
    }
    __syncthreads();
    for (int i = tid; i < total; i += 256) atomicAdd(&h[buf[i].x & (BROWS - 1)], 1);
    __syncthreads();
    if (tid == 0) {
        int run = 0;
        #pragma unroll
        for (int r = 0; r < BROWS; ++r) { pref[r] = run; run += h[r]; }
    }
    __syncthreads();
    uint2* dst = bbuf + (size_t)b * WIN;
    for (int i = tid; i < total; i += 256) {
        unsigned m = buf[i].x;
        int rl = (int)(m & (BROWS - 1));
        int pos = pref[rl] + atomicAdd(&fill[rl], 1);
        uint2 pk;
        pk.x = m >> BSHIFT;
        pk.y = buf[i].y;
        dst[pos] = pk;
    }
    if (tid < BROWS) {
        int row = b * BROWS + tid;
        if (row < NN) { row_start[row] = b * WIN + pref[tid]; row_cnt[row] = h[tid]; }
    }
}

// ---------- fused CSR SpMM (wave per row, reg accumulation, bf16 gather) ----------
__global__ __launch_bounds__(256) void spmm_csr_fused(const int* __restrict__ row_start,
                                                      const int* __restrict__ row_cnt,
                                                      const uint2* __restrict__ csr,
                                                      const unsigned short* __restrict__ x,
                                                      const float* __restrict__ noise_k,
                                                      unsigned short* __restrict__ ego_out,
                                                      float* __restrict__ acc,
                                                      int mode) {
    int row = (blockIdx.x * 256 + threadIdx.x) >> 6;
    int lane = threadIdx.x & 63;
    if (row >= NN) return;
    int s = row_start[row];
    int end = s + row_cnt[row];

    float a0 = 0.f, a1 = 0.f, a2 = 0.f, a3 = 0.f;
    float a4 = 0.f, a5 = 0.f, a6 = 0.f, a7 = 0.f;
    int e = s;
    for (; e + 8 <= end; e += 8) {
        uint2 p0 = csr[e],     p1 = csr[e + 1], p2 = csr[e + 2], p3 = csr[e + 3];
        uint2 p4 = csr[e + 4], p5 = csr[e + 5], p6 = csr[e + 6], p7 = csr[e + 7];
        a0 += __uint_as_float(p0.y) * bf16_to_f32(x[(size_t)p0.x * EMB + lane]);
        a1 += __uint_as_float(p1.y) * bf16_to_f32(x[(size_t)p1.x * EMB + lane]);
        a2 += __uint_as_float(p2.y) * bf16_to_f32(x[(size_t)p2.x * EMB + lane]);
        a3 += __uint_as_float(p3.y) * bf16_to_f32(x[(size_t)p3.x * EMB + lane]);
        a4 += __uint_as_float(p4.y) * bf16_to_f32(x[(size_t)p4.x * EMB + lane]);
        a5 += __uint_as_float(p5.y) * bf16_to_f32(x[(size_t)p5.x * EMB + lane]);
        a6 += __uint_as_float(p6.y) * bf16_to_f32(x[(size_t)p6.x * EMB + lane]);
        a7 += __uint_as_float(p7.y) * bf16_to_f32(x[(size_t)p7.x * EMB + lane]);
    }
    for (; e < end; ++e) {
        uint2 p = csr[e];
        a0 += __uint_as_float(p.y) * bf16_to_f32(x[(size_t)p.x * EMB + lane]);
    }
    float a = ((a0 + a1) + (a2 + a3)) + ((a4 + a5) + (a6 + a7));

    size_t idx = (size_t)row * EMB + lane;
    float nv = noise_k[idx];
    float ss = nv * nv;
    #pragma unroll
    for (int off = 32; off >= 1; off >>= 1) ss += __shfl_xor(ss, off, 64);
    float nrm = fmaxf(sqrtf(ss), 1e-12f);
    float sgn = (a > 0.0f) ? 1.0f : ((a < 0.0f) ? -1.0f : 0.0f);
    float e1 = a + sgn * (nv / nrm) * EPS_C;

    ego_out[idx] = f32_to_bf16_rne(e1);
    if (mode == 0)      acc[idx] = e1;
    else if (mode == 1) acc[idx] += e1;
    else                acc[idx] = (acc[idx] + e1) * (1.0f / 3.0f);
}

// ---------- fallback: fp32 atomic path (needs 76.8 MB ws) ----------
__global__ __launch_bounds__(256) void concat_f32_kernel(const float* __restrict__ u,
                                                         const float* __restrict__ it,
                                                         float* __restrict__ out) {
    long i = (long)blockIdx.x * 256 + threadIdx.x;
    const long usz = (long)USER_NUM * EMB;
    const long tot = (long)NN * EMB;
    if (i >= tot) return;
    out[i] = (i < usz) ? u[i] : it[i - usz];
}

__global__ __launch_bounds__(256) void spmm_atomic_kernel(const int* __restrict__ rows,
                                                          const int* __restrict__ cols,
                                                          const float* __restrict__ vals,
                                                          const float* __restrict__ x,
                                                          float* __restrict__ y) {
    long t = (long)blockIdx.x * 256 + threadIdx.x;
    int e = (int)(t >> 6);
    int lane = (int)(t & 63);
    if (e >= N_EDGES) return;
    atomicAdd(&y[(long)rows[e] * EMB + lane], vals[e] * x[(long)cols[e] * EMB + lane]);
}

__global__ __launch_bounds__(256) void noise_acc_kernel(float* __restrict__ ego,
                                                        const float* __restrict__ noise_k,
                                                        float* __restrict__ acc,
                                                        int mode) {
    long t = (long)blockIdx.x * 256 + threadIdx.x;
    int node = (int)(t >> 6);
    int lane = (int)(t & 63);
    if (node >= NN) return;
    long idx = (long)node * EMB + lane;
    float nv = noise_k[idx];
    float s = nv * nv;
    #pragma unroll
    for (int off = 32; off >= 1; off >>= 1) s += __shfl_xor(s, off, 64);
    float nrm = fmaxf(sqrtf(s), 1e-12f);
    float e0 = ego[idx];
    float sgn = (e0 > 0.0f) ? 1.0f : ((e0 < 0.0f) ? -1.0f : 0.0f);
    float e1 = e0 + sgn * (nv / nrm) * EPS_C;
    ego[idx] = e1;
    if (mode == 0)      acc[idx] = e1;
    else if (mode == 1) acc[idx] += e1;
    else                acc[idx] = (acc[idx] + e1) * (1.0f / 3.0f);
}

extern "C" void kernel_launch(void* const* d_in, const int* in_sizes, int n_in,
                              void* d_out, int out_size, void* d_ws, size_t ws_size,
                              hipStream_t stream) {
    const float* user_emb   = (const float*)d_in[0];
    const float* item_emb   = (const float*)d_in[1];
    const float* user_proto = (const float*)d_in[2];
    const float* item_proto = (const float*)d_in[3];
    const int*   rows       = (const int*)d_in[4];
    const int*   cols       = (const int*)d_in[5];
    const float* vals       = (const float*)d_in[6];
    const float* noise      = (const float*)d_in[7];
    float* out = (float*)d_out;

    const size_t EGO_BF = ((size_t)NN * EMB * sizeof(unsigned short) + 255) & ~(size_t)255;
    const size_t NARR   = ((size_t)NN * sizeof(int) + 255) & ~(size_t)255;

    // ---- new path layout (~176.5 MB) ----
    const size_t SBUF_SZ  = (size_t)NSB * SCAP * sizeof(uint2);      // 66.0 MB
    const size_t BBUF2_SZ = (size_t)NB * BCAP * sizeof(uint2);       // 70.8 MB
    const size_t SFILL_SZ = ((size_t)NSB * SF_STRIDE * sizeof(int) + 255) & ~(size_t)255;
    const size_t BFILL2_SZ= ((size_t)NB * sizeof(int) + 255) & ~(size_t)255;
    const size_t required_new = 2 * EGO_BF + SBUF_SZ + BBUF2_SZ + 2 * NARR + SFILL_SZ + BFILL2_SZ;

    // ---- old path layout (~131 MB) ----
    const size_t BBUF   = (size_t)NB * WIN * sizeof(uint2);
    const size_t FARR   = ((size_t)NB * NSUB * sizeof(int) + 255) & ~(size_t)255;
    const size_t required_old = 2 * EGO_BF + BBUF + 2 * NARR + FARR;

    float* acc = out;
    const int elemTotal  = NN * EMB;
    const int elemBlocks = (elemTotal + 255) / 256;
    const int vecBlocks  = (elemTotal / 4 + 255) / 256;
    const int edgeBlocks = (N_EDGES + 255) / 256;
    const int rowWaveBlocks = (NN + 3) / 4;

    if (ws_size >= required_new) {
        char* p = (char*)d_ws;
        unsigned short* egoA = (unsigned short*)p;  p += EGO_BF;
        unsigned short* egoB = (unsigned short*)p;  p += EGO_BF;
        uint2* sbuf          = (uint2*)p;           p += SBUF_SZ;
        uint2* bbuf2         = (uint2*)p;           p += BBUF2_SZ;
        int* row_start       = (int*)p;             p += NARR;
        int* row_cnt         = (int*)p;             p += NARR;
        int* sfill           = (int*)p;             p += SFILL_SZ;
        int* bfill2          = (int*)p;             p += BFILL2_SZ;

        concat_bf16_kernel<<<vecBlocks, 256, 0, stream>>>(user_emb, item_emb, egoA);
        hipMemsetAsync(sfill, 0, (size_t)NSB * SF_STRIDE * sizeof(int), stream);
        chunk_sort_scatter<<<NCH, 256, 0, stream>>>(rows, cols, vals, sfill, sbuf);
        l2_split<<<NSB, 256, 0, stream>>>(sfill, sbuf, bfill2, bbuf2);
        bucket_sort_single<<<NB, 256, 0, stream>>>(bfill2, bbuf2, row_start, row_cnt);

        unsigned short* cur = egoA;
        unsigned short* nxt = egoB;
        for (int k = 0; k < 3; ++k) {
            int mode = (k == 0) ? 0 : ((k == 2) ? 2 : 1);
            spmm_csr_fused<<<rowWaveBlocks, 256, 0, stream>>>(
                row_start, row_cnt, bbuf2, cur,
                noise + (size_t)k * NN * EMB, nxt, acc, mode);
            unsigned short* t = cur; cur = nxt; nxt = t;
        }
    } else if (ws_size >= required_old) {
        char* p = (char*)d_ws;
        unsigned short* egoA = (unsigned short*)p;  p += EGO_BF;
        unsigned short* egoB = (unsigned short*)p;  p += EGO_BF;
        uint2* bbuf          = (uint2*)p;           p += BBUF;
        int* row_start       = (int*)p;             p += NARR;
        int* row_cnt         = (int*)p;             p += NARR;
        int* bfill           = (int*)p;             p += FARR;

        concat_bf16_kernel<<<vecBlocks, 256, 0, stream>>>(user_emb, item_emb, egoA);
        hipMemsetAsync(bfill, 0, (size_t)NB * NSUB * sizeof(int), stream);
        bucket_scatter_fixed<<<edgeBlocks, 256, 0, stream>>>(rows, cols, vals, bfill, bbuf);
        bucket_sort_fixed<<<NB, 256, 0, stream>>>(bfill, bbuf, row_start, row_cnt);

        unsigned short* cur = egoA;
        unsigned short* nxt = egoB;
        for (int k = 0; k < 3; ++k) {
            int mode = (k == 0) ? 0 : ((k == 2) ? 2 : 1);
            spmm_csr_fused<<<rowWaveBlocks, 256, 0, stream>>>(
                row_start, row_cnt, bbuf, cur,
                noise + (size_t)k * NN * EMB, nxt, acc, mode);
            unsigned short* t = cur; cur = nxt; nxt = t;
        }
    } else {
        const size_t EGO_SZ = (size_t)NN * EMB * sizeof(float);
        float* fA = (float*)d_ws;
        float* fB = (float*)((char*)d_ws + EGO_SZ);
        concat_f32_kernel<<<elemBlocks, 256, 0, stream>>>(user_emb, item_emb, fA);
        float* cur = fA; float* nxt = fB;
        for (int k = 0; k < 3; ++k) {
            hipMemsetAsync(nxt, 0, EGO_SZ, stream);
            spmm_atomic_kernel<<<N_EDGES / 4, 256, 0, stream>>>(rows, cols, vals, cur, nxt);
            int mode = (k == 0) ? 0 : ((k == 2) ? 2 : 1);
            noise_acc_kernel<<<elemBlocks, 256, 0, stream>>>(
                nxt, noise + (size_t)k * NN * EMB, acc, mode);
            float* t = cur; cur = nxt; nxt = t;
        }
    }

    hipMemcpyAsync(out + (size_t)NN * EMB, user_proto,
                   (size_t)PROTO * EMB * sizeof(float), hipMemcpyDeviceToDevice, stream);
    hipMemcpyAsync(out + (size_t)NN * EMB + (size_t)PROTO * EMB, item_proto,
                   (size_t)PROTO * EMB * sizeof(float), hipMemcpyDeviceToDevice, stream);
}

// Round 3
// 931.305 us; speedup vs baseline: 1.6942x; 1.2292x over previous
//
#include <hip/hip_runtime.h>

#define USER_NUM 100000
#define ITEM_NUM 50000
#define NN (USER_NUM + ITEM_NUM)
#define EMB 64
#define N_EDGES 8000000
#define EPS_C 0.1f
#define PROTO 4000

// ---------------- old-path params (kept verbatim as ws fallback) ----------------
#define BSHIFT 6
#define BROWS 64                                // rows per bucket
#define NB ((NN + BROWS - 1) / BROWS)           // 2344 buckets
#define NSUB 8
#define CAPS 608
#define WIN (NSUB * CAPS)
#define CAP 4608

// ---------------- hierarchical split params ----------------
#define SBSHIFT 9
#define SBROWS 512                              // rows per super-bin
#define NSB ((NN + SBROWS - 1) / SBROWS)        // 293 super-bins
#define SCAP 28160                              // slots/super-bin; mean 27304, +5.2 sigma
#define SF_STRIDE 16                            // pad sfill counters to one 64B line each
// chunk-sort scatter
#define CHS 8192                                // edges per block chunk (LDS-resident)
#define NCH ((N_EDGES + CHS - 1) / CHS)         // 977 blocks

static __device__ __forceinline__ unsigned short f32_to_bf16_rne(float f) {
    unsigned u = __float_as_uint(f);
    u += 0x7FFFu + ((u >> 16) & 1u);
    return (unsigned short)(u >> 16);
}
static __device__ __forceinline__ float bf16_to_f32(unsigned short h) {
    return __uint_as_float(((unsigned)h) << 16);
}

// ---------- concat + quantize to bf16 (float4 -> ushort4) ----------
__global__ __launch_bounds__(256) void concat_bf16_kernel(const float* __restrict__ u,
                                                          const float* __restrict__ it,
                                                          unsigned short* __restrict__ out) {
    long i4 = (long)blockIdx.x * 256 + threadIdx.x;
    const long usz4 = (long)USER_NUM * EMB / 4;
    const long tot4 = (long)NN * EMB / 4;
    if (i4 >= tot4) return;
    const float4* src = (i4 < usz4) ? (const float4*)u : (const float4*)it;
    long j = (i4 < usz4) ? i4 : (i4 - usz4);
    float4 v = src[j];
    ushort4 o;
    o.x = f32_to_bf16_rne(v.x); o.y = f32_to_bf16_rne(v.y);
    o.z = f32_to_bf16_rne(v.z); o.w = f32_to_bf16_rne(v.w);
    ((ushort4*)out)[i4] = o;
}

// ================= chunk counting-sort scatter (single shot per block) =================
__global__ __launch_bounds__(256) void chunk_sort_scatter(const int* __restrict__ rows,
                                                          const int* __restrict__ cols,
                                                          const float* __restrict__ vals,
                                                          int* __restrict__ sfill,
                                                          uint2* __restrict__ sbuf) {
    __shared__ unsigned skey[CHS];              // 32 KB
    __shared__ unsigned sval[CHS];              // 32 KB
    __shared__ int hist[NSB];
    __shared__ int pref[NSB + 1];
    __shared__ int gbase[NSB];
    __shared__ int fill[NSB];

    const int tid   = threadIdx.x;
    const int start = blockIdx.x * CHS;
    const int n     = (start + CHS <= N_EDGES) ? CHS : (N_EDGES - start);
    const int n4    = n >> 2;                   // all chunk sizes are multiples of 4

    for (int b = tid; b < NSB; b += 256) { hist[b] = 0; fill[b] = 0; }
    __syncthreads();

    // phase 1: histogram (vectorized row read)
    const int4* rows4 = (const int4*)(rows + start);
    for (int i = tid; i < n4; i += 256) {
        int4 r = rows4[i];
        atomicAdd(&hist[r.x >> SBSHIFT], 1);
        atomicAdd(&hist[r.y >> SBSHIFT], 1);
        atomicAdd(&hist[r.z >> SBSHIFT], 1);
        atomicAdd(&hist[r.w >> SBSHIFT], 1);
    }
    __syncthreads();

    // exclusive prefix scan over 293 bins: wave-0 shuffle scan
    if (tid < 64) {
        int carry = 0;
        #pragma unroll
        for (int g = 0; g < (NSB + 63) / 64; ++g) {
            int idx = g * 64 + tid;
            int h = (idx < NSB) ? hist[idx] : 0;
            int v = h;
            #pragma unroll
            for (int off = 1; off < 64; off <<= 1) {
                int t = __shfl_up(v, off, 64);
                if (tid >= off) v += t;
            }
            if (idx < NSB) pref[idx] = carry + v - h;
            carry += __shfl(v, 63, 64);
        }
        if (tid == 0) pref[NSB] = carry;
    }
    __syncthreads();

    // reserve global space: one padded-line atomic per non-empty (block,bin)
    for (int b = tid; b < NSB; b += 256)
        gbase[b] = hist[b] ? atomicAdd(&sfill[b * SF_STRIDE], hist[b]) : 0;

    // phase 2: scatter edges into LDS at sorted positions
    const int4*   cols4 = (const int4*)(cols + start);
    const float4* vals4 = (const float4*)(vals + start);
    for (int i = tid; i < n4; i += 256) {
        int4   r = rows4[i];
        int4   c = cols4[i];
        float4 v = vals4[i];
        {
            int b = r.x >> SBSHIFT; int p = pref[b] + atomicAdd(&fill[b], 1);
            skey[p] = ((unsigned)r.x & (SBROWS - 1)) | ((unsigned)c.x << SBSHIFT);
            sval[p] = __float_as_uint(v.x);
        }
        {
            int b = r.y >> SBSHIFT; int p = pref[b] + atomicAdd(&fill[b], 1);
            skey[p] = ((unsigned)r.y & (SBROWS - 1)) | ((unsigned)c.y << SBSHIFT);
            sval[p] = __float_as_uint(v.y);
        }
        {
            int b = r.z >> SBSHIFT; int p = pref[b] + atomicAdd(&fill[b], 1);
            skey[p] = ((unsigned)r.z & (SBROWS - 1)) | ((unsigned)c.z << SBSHIFT);
            sval[p] = __float_as_uint(v.z);
        }
        {
            int b = r.w >> SBSHIFT; int p = pref[b] + atomicAdd(&fill[b], 1);
            skey[p] = ((unsigned)r.w & (SBROWS - 1)) | ((unsigned)c.w << SBSHIFT);
            sval[p] = __float_as_uint(v.w);
        }
    }
    __syncthreads();

    // phase 3: stream sorted chunk out; consecutive threads -> consecutive slots
    for (int j = tid; j < n; j += 256) {
        int lo = 0, hi = NSB;                   // largest b with pref[b] <= j
        while (hi - lo > 1) {
            int mid = (lo + hi) >> 1;
            if (pref[mid] <= j) lo = mid; else hi = mid;
        }
        int gpos = gbase[lo] + (j - pref[lo]);
        if (gpos < SCAP) {
            uint2 pk; pk.x = skey[j]; pk.y = sval[j];
            sbuf[(size_t)lo * SCAP + gpos] = pk;
        }
    }
}

// ================= per-super-bin row sort (fuses old l2_split + bucket_sort) =============
// One block per super-bin: histogram its 512 rows, prefix-scan, scatter edges directly
// to final row-sorted positions, emit row_start/row_cnt. 3 barriers total.
__global__ __launch_bounds__(512) void bin_rowsort(const int* __restrict__ sfill,
                                                   const uint2* __restrict__ sbuf,
                                                   uint2* __restrict__ dst,
                                                   int* __restrict__ row_start,
                                                   int* __restrict__ row_cnt) {
    __shared__ int hist[SBROWS], pref[SBROWS], fill[SBROWS];   // 6 KB
    const int s = blockIdx.x, tid = threadIdx.x;
    int total = sfill[s * SF_STRIDE]; if (total > SCAP) total = SCAP;
    const uint2* src = sbuf + (size_t)s * SCAP;

    for (int r = tid; r < SBROWS; r += 512) { hist[r] = 0; fill[r] = 0; }
    __syncthreads();

    const int n2 = total >> 1;
    const uint4* src4 = (const uint4*)src;      // window base is 16B-aligned
    for (int i = tid; i < n2; i += 512) {
        uint4 q = src4[i];
        atomicAdd(&hist[q.x & (SBROWS - 1)], 1);
        atomicAdd(&hist[q.z & (SBROWS - 1)], 1);
    }
    if (tid == 0 && (total & 1)) atomicAdd(&hist[src[total - 1].x & (SBROWS - 1)], 1);
    __syncthreads();

    if (tid < 64) {
        int carry = 0;
        #pragma unroll
        for (int g = 0; g < SBROWS / 64; ++g) {
            int idx = g * 64 + tid;
            int h = hist[idx];
            int v = h;
            #pragma unroll
            for (int off = 1; off < 64; off <<= 1) {
                int t = __shfl_up(v, off, 64);
                if (tid >= off) v += t;
            }
            pref[idx] = carry + v - h;
            carry += __shfl(v, 63, 64);
        }
    }
    __syncthreads();

    uint2* dwin = dst + (size_t)s * SCAP;
    for (int i = tid; i < n2; i += 512) {
        uint4 q = src4[i];
        {
            int r = (int)(q.x & (SBROWS - 1));
            int p = pref[r] + atomicAdd(&fill[r], 1);
            uint2 o; o.x = q.x >> SBSHIFT; o.y = q.y;   // {col, valbits}
            dwin[p] = o;
        }
        {
            int r = (int)(q.z & (SBROWS - 1));
            int p = pref[r] + atomicAdd(&fill[r], 1);
            uint2 o; o.x = q.z >> SBSHIFT; o.y = q.w;
            dwin[p] = o;
        }
    }
    if (tid == 0 && (total & 1)) {
        uint2 pk = src[total - 1];
        int r = (int)(pk.x & (SBROWS - 1));
        int p = pref[r] + atomicAdd(&fill[r], 1);
        uint2 o; o.x = pk.x >> SBSHIFT; o.y = pk.y;
        dwin[p] = o;
    }
    if (tid < SBROWS) {
        int row = s * SBROWS + tid;
        if (row < NN) { row_start[row] = s * SCAP + pref[tid]; row_cnt[row] = hist[tid]; }
    }
}

// ---------- fused CSR SpMM: 4 edges/wave-instr (16 lanes x 4 bf16 per edge-row) ----------
// slot = lane>>4 picks 1 of 4 concurrent edges; m = lane&15 picks dims 4m..4m+3.
// One csr load covers 4 edges, one uint2 gather covers 4 full x-rows per wave.
__global__ __launch_bounds__(256) void spmm_csr_fused(const int* __restrict__ row_start,
                                                      const int* __restrict__ row_cnt,
                                                      const uint2* __restrict__ csr,
                                                      const unsigned short* __restrict__ x,
                                                      const float* __restrict__ noise_k,
                                                      unsigned short* __restrict__ ego_out,
                                                      float* __restrict__ acc,
                                                      int mode) {
    int row  = (blockIdx.x * 256 + threadIdx.x) >> 6;
    int lane = threadIdx.x & 63;
    if (row >= NN) return;
    const int slot = lane >> 4;
    const int moff = (lane & 15) << 2;          // element offset of this lane's 4 dims

    int s   = row_start[row];
    int end = s + row_cnt[row];

    float ax = 0.f, ay = 0.f, az = 0.f, aw = 0.f;
    float bx = 0.f, by = 0.f, bz = 0.f, bw = 0.f;
    int e = s;
    for (; e + 8 <= end; e += 8) {
        uint2 pA = csr[e + slot];
        uint2 pB = csr[e + 4 + slot];
        uint2 gA = *(const uint2*)(x + (((unsigned)pA.x) << 6) + moff);
        uint2 gB = *(const uint2*)(x + (((unsigned)pB.x) << 6) + moff);
        float vA = __uint_as_float(pA.y);
        float vB = __uint_as_float(pB.y);
        ax += vA * __uint_as_float(gA.x << 16);
        ay += vA * __uint_as_float(gA.x & 0xFFFF0000u);
        az += vA * __uint_as_float(gA.y << 16);
        aw += vA * __uint_as_float(gA.y & 0xFFFF0000u);
        bx += vB * __uint_as_float(gB.x << 16);
        by += vB * __uint_as_float(gB.x & 0xFFFF0000u);
        bz += vB * __uint_as_float(gB.y << 16);
        bw += vB * __uint_as_float(gB.y & 0xFFFF0000u);
    }
    for (; e < end; e += 4) {                   // masked tail groups
        int idx = e + slot;
        uint2 p = make_uint2(0u, 0u);
        if (idx < end) p = csr[idx];
        uint2 g = *(const uint2*)(x + (((unsigned)p.x) << 6) + moff);
        float v = __uint_as_float(p.y);         // 0 for masked lanes
        ax += v * __uint_as_float(g.x << 16);
        ay += v * __uint_as_float(g.x & 0xFFFF0000u);
        az += v * __uint_as_float(g.y << 16);
        aw += v * __uint_as_float(g.y & 0xFFFF0000u);
    }
    ax += bx; ay += by; az += bz; aw += bw;

    // combine the 4 slots: dims 4m..4m+3 summed across slot groups
    #pragma unroll
    for (int off = 16; off < 64; off <<= 1) {
        ax += __shfl_xor(ax, off, 64);
        ay += __shfl_xor(ay, off, 64);
        az += __shfl_xor(az, off, 64);
        aw += __shfl_xor(aw, off, 64);
    }

    if (slot == 0) {                            // 16 lanes handle the full row, 4 dims each
        size_t v4 = (size_t)row * 16 + (lane & 15);
        float4 nv = ((const float4*)noise_k)[v4];
        float ss = nv.x * nv.x + nv.y * nv.y + nv.z * nv.z + nv.w * nv.w;
        #pragma unroll
        for (int off = 1; off < 16; off <<= 1) ss += __shfl_xor(ss, off, 64);
        float inv = EPS_C / fmaxf(sqrtf(ss), 1e-12f);

        float sx = (ax > 0.f) ? 1.f : ((ax < 0.f) ? -1.f : 0.f);
        float sy = (ay > 0.f) ? 1.f : ((ay < 0.f) ? -1.f : 0.f);
        float sz = (az > 0.f) ? 1.f : ((az < 0.f) ? -1.f : 0.f);
        float sw = (aw > 0.f) ? 1.f : ((aw < 0.f) ? -1.f : 0.f);
        float4 e1;
        e1.x = fmaf(sx * nv.x, inv, ax);
        e1.y = fmaf(sy * nv.y, inv, ay);
        e1.z = fmaf(sz * nv.z, inv, az);
        e1.w = fmaf(sw * nv.w, inv, aw);

        ushort4 o;
        o.x = f32_to_bf16_rne(e1.x); o.y = f32_to_bf16_rne(e1.y);
        o.z = f32_to_bf16_rne(e1.z); o.w = f32_to_bf16_rne(e1.w);
        ((ushort4*)ego_out)[v4] = o;

        float4* accp = (float4*)acc + v4;
        if (mode == 0) {
            *accp = e1;
        } else if (mode == 1) {
            float4 a0 = *accp;
            a0.x += e1.x; a0.y += e1.y; a0.z += e1.z; a0.w += e1.w;
            *accp = a0;
        } else {
            float4 a0 = *accp;
            a0.x = (a0.x + e1.x) * (1.0f / 3.0f);
            a0.y = (a0.y + e1.y) * (1.0f / 3.0f);
            a0.z = (a0.z + e1.z) * (1.0f / 3.0f);
            a0.w = (a0.w + e1.w) * (1.0f / 3.0f);
            *accp = a0;
        }
    }
}

// ================= OLD PATH (verbatim fallback) =================
__global__ __launch_bounds__(256) void bucket_scatter_fixed(const int* __restrict__ rows,
                                                            const int* __restrict__ cols,
                                                            const float* __restrict__ vals,
                                                            int* __restrict__ bfill,
                                                            uint2* __restrict__ bbuf) {
    int e = blockIdx.x * 256 + threadIdx.x;
    if (e >= N_EDGES) return;
    int sub = blockIdx.x & (NSUB - 1);
    int r = rows[e];
    int b = r >> BSHIFT;
    int pos = atomicAdd(&bfill[b * NSUB + sub], 1);
    if (pos < CAPS) {
        uint2 pk;
        pk.x = (unsigned)(r & (BROWS - 1)) | ((unsigned)cols[e] << BSHIFT);
        pk.y = __float_as_uint(vals[e]);
        bbuf[(size_t)b * WIN + sub * CAPS + pos] = pk;
    }
}

__global__ __launch_bounds__(256) void bucket_sort_fixed(const int* __restrict__ bfill,
                                                         uint2* __restrict__ bbuf,
                                                         int* __restrict__ row_start,
                                                         int* __restrict__ row_cnt) {
    __shared__ uint2 buf[CAP];
    __shared__ int scnt[NSUB], soff[NSUB];
    __shared__ int h[BROWS], pref[BROWS], fill[BROWS];
    int b = blockIdx.x;
    int tid = threadIdx.x;
    if (tid < NSUB) {
        int c = bfill[b * NSUB + tid];
        scnt[tid] = (c < CAPS) ? c : CAPS;
    }
    if (tid < BROWS) { h[tid] = 0; fill[tid] = 0; }
    __syncthreads();
    if (tid == 0) {
        int run = 0;
        #pragma unroll
        for (int s = 0; s < NSUB; ++s) { soff[s] = run; run += scnt[s]; }
    }
    __syncthreads();
    int total = soff[NSUB - 1] + scnt[NSUB - 1];
    if (total > CAP) total = CAP;
    for (int s = 0; s < NSUB; ++s) {
        int c = scnt[s], off = soff[s];
        const uint2* src = bbuf + (size_t)b * WIN + s * CAPS;
        for (int i = tid; i < c; i += 256)
            if (off + i < CAP) buf[off + i] = src[i];
    }
    __syncthreads();
    for (int i = tid; i < total; i += 256) atomicAdd(&h[buf[i].x & (BROWS - 1)], 1);
    __syncthreads();
    if (tid == 0) {
        int run = 0;
        #pragma unroll
        for (int r = 0; r < BROWS; ++r) { pref[r] = run; run += h[r]; }
    }
    __syncthreads();
    uint2* dst = bbuf + (size_t)b * WIN;
    for (int i = tid; i < total; i += 256) {
        unsigned m = buf[i].x;
        int rl = (int)(m & (BROWS - 1));
        int pos = pref[rl] + atomicAdd(&fill[rl], 1);
        uint2 pk;
        pk.x = m >> BSHIFT;
        pk.y = buf[i].y;
        dst[pos] = pk;
    }
    if (tid < BROWS) {
        int row = b * BROWS + tid;
        if (row < NN) { row_start[row] = b * WIN + pref[tid]; row_cnt[row] = h[tid]; }
    }
}

// old-path spmm (wave-per-row, scalar bf16 gather) — kept for fallback branch
__global__ __launch_bounds__(256) void spmm_csr_old(const int* __restrict__ row_start,
                                                    const int* __restrict__ row_cnt,
                                                    const uint2* __restrict__ csr,
                                                    const unsigned short* __restrict__ x,
                                                    const float* __restrict__ noise_k,
                                                    unsigned short* __restrict__ ego_out,
                                                    float* __restrict__ acc,
                                                    int mode) {
    int row = (blockIdx.x * 256 + threadIdx.x) >> 6;
    int lane = threadIdx.x & 63;
    if (row >= NN) return;
    int s = row_start[row];
    int end = s + row_cnt[row];
    float a0 = 0.f, a1 = 0.f, a2 = 0.f, a3 = 0.f;
    int e = s;
    for (; e + 4 <= end; e += 4) {
        uint2 p0 = csr[e], p1 = csr[e + 1], p2 = csr[e + 2], p3 = csr[e + 3];
        a0 += __uint_as_float(p0.y) * bf16_to_f32(x[(size_t)p0.x * EMB + lane]);
        a1 += __uint_as_float(p1.y) * bf16_to_f32(x[(size_t)p1.x * EMB + lane]);
        a2 += __uint_as_float(p2.y) * bf16_to_f32(x[(size_t)p2.x * EMB + lane]);
        a3 += __uint_as_float(p3.y) * bf16_to_f32(x[(size_t)p3.x * EMB + lane]);
    }
    for (; e < end; ++e) {
        uint2 p = csr[e];
        a0 += __uint_as_float(p.y) * bf16_to_f32(x[(size_t)p.x * EMB + lane]);
    }
    float a = (a0 + a1) + (a2 + a3);
    size_t idx = (size_t)row * EMB + lane;
    float nv = noise_k[idx];
    float ss = nv * nv;
    #pragma unroll
    for (int off = 32; off >= 1; off >>= 1) ss += __shfl_xor(ss, off, 64);
    float nrm = fmaxf(sqrtf(ss), 1e-12f);
    float sgn = (a > 0.0f) ? 1.0f : ((a < 0.0f) ? -1.0f : 0.0f);
    float e1 = a + sgn * (nv / nrm) * EPS_C;
    ego_out[idx] = f32_to_bf16_rne(e1);
    if (mode == 0)      acc[idx] = e1;
    else if (mode == 1) acc[idx] += e1;
    else                acc[idx] = (acc[idx] + e1) * (1.0f / 3.0f);
}

// ---------- fallback: fp32 atomic path (needs 76.8 MB ws) ----------
__global__ __launch_bounds__(256) void concat_f32_kernel(const float* __restrict__ u,
                                                         const float* __restrict__ it,
                                                         float* __restrict__ out) {
    long i = (long)blockIdx.x * 256 + threadIdx.x;
    const long usz = (long)USER_NUM * EMB;
    const long tot = (long)NN * EMB;
    if (i >= tot) return;
    out[i] = (i < usz) ? u[i] : it[i - usz];
}

__global__ __launch_bounds__(256) void spmm_atomic_kernel(const int* __restrict__ rows,
                                                          const int* __restrict__ cols,
                                                          const float* __restrict__ vals,
                                                          const float* __restrict__ x,
                                                          float* __restrict__ y) {
    long t = (long)blockIdx.x * 256 + threadIdx.x;
    int e = (int)(t >> 6);
    int lane = (int)(t & 63);
    if (e >= N_EDGES) return;
    atomicAdd(&y[(long)rows[e] * EMB + lane], vals[e] * x[(long)cols[e] * EMB + lane]);
}

__global__ __launch_bounds__(256) void noise_acc_kernel(float* __restrict__ ego,
                                                        const float* __restrict__ noise_k,
                                                        float* __restrict__ acc,
                                                        int mode) {
    long t = (long)blockIdx.x * 256 + threadIdx.x;
    int node = (int)(t >> 6);
    int lane = (int)(t & 63);
    if (node >= NN) return;
    long idx = (long)node * EMB + lane;
    float nv = noise_k[idx];
    float s = nv * nv;
    #pragma unroll
    for (int off = 32; off >= 1; off >>= 1) s += __shfl_xor(s, off, 64);
    float nrm = fmaxf(sqrtf(s), 1e-12f);
    float e0 = ego[idx];
    float sgn = (e0 > 0.0f) ? 1.0f : ((e0 < 0.0f) ? -1.0f : 0.0f);
    float e1 = e0 + sgn * (nv / nrm) * EPS_C;
    ego[idx] = e1;
    if (mode == 0)      acc[idx] = e1;
    else if (mode == 1) acc[idx] += e1;
    else                acc[idx] = (acc[idx] + e1) * (1.0f / 3.0f);
}

extern "C" void kernel_launch(void* const* d_in, const int* in_sizes, int n_in,
                              void* d_out, int out_size, void* d_ws, size_t ws_size,
                              hipStream_t stream) {
    const float* user_emb   = (const float*)d_in[0];
    const float* item_emb   = (const float*)d_in[1];
    const float* user_proto = (const float*)d_in[2];
    const float* item_proto = (const float*)d_in[3];
    const int*   rows       = (const int*)d_in[4];
    const int*   cols       = (const int*)d_in[5];
    const float* vals       = (const float*)d_in[6];
    const float* noise      = (const float*)d_in[7];
    float* out = (float*)d_out;

    const size_t EGO_BF = ((size_t)NN * EMB * sizeof(unsigned short) + 255) & ~(size_t)255;
    const size_t NARR   = ((size_t)NN * sizeof(int) + 255) & ~(size_t)255;

    // ---- new path layout (~172 MB) ----
    const size_t SBUF_SZ  = (size_t)NSB * SCAP * sizeof(uint2);      // 66.0 MB
    const size_t DST_SZ   = (size_t)NSB * SCAP * sizeof(uint2);      // 66.0 MB (row-sorted)
    const size_t SFILL_SZ = ((size_t)NSB * SF_STRIDE * sizeof(int) + 255) & ~(size_t)255;
    const size_t required_new = 2 * EGO_BF + SBUF_SZ + DST_SZ + 2 * NARR + SFILL_SZ;

    // ---- old path layout (~131 MB) ----
    const size_t BBUF   = (size_t)NB * WIN * sizeof(uint2);
    const size_t FARR   = ((size_t)NB * NSUB * sizeof(int) + 255) & ~(size_t)255;
    const size_t required_old = 2 * EGO_BF + BBUF + 2 * NARR + FARR;

    float* acc = out;
    const int elemTotal  = NN * EMB;
    const int elemBlocks = (elemTotal + 255) / 256;
    const int vecBlocks  = (elemTotal / 4 + 255) / 256;
    const int edgeBlocks = (N_EDGES + 255) / 256;
    const int rowWaveBlocks = (NN + 3) / 4;

    if (ws_size >= required_new) {
        char* p = (char*)d_ws;
        unsigned short* egoA = (unsigned short*)p;  p += EGO_BF;
        unsigned short* egoB = (unsigned short*)p;  p += EGO_BF;
        uint2* sbuf          = (uint2*)p;           p += SBUF_SZ;
        uint2* dstbuf        = (uint2*)p;           p += DST_SZ;
        int* row_start       = (int*)p;             p += NARR;
        int* row_cnt         = (int*)p;             p += NARR;
        int* sfill           = (int*)p;             p += SFILL_SZ;

        concat_bf16_kernel<<<vecBlocks, 256, 0, stream>>>(user_emb, item_emb, egoA);
        hipMemsetAsync(sfill, 0, (size_t)NSB * SF_STRIDE * sizeof(int), stream);
        chunk_sort_scatter<<<NCH, 256, 0, stream>>>(rows, cols, vals, sfill, sbuf);
        bin_rowsort<<<NSB, 512, 0, stream>>>(sfill, sbuf, dstbuf, row_start, row_cnt);

        unsigned short* cur = egoA;
        unsigned short* nxt = egoB;
        for (int k = 0; k < 3; ++k) {
            int mode = (k == 0) ? 0 : ((k == 2) ? 2 : 1);
            spmm_csr_fused<<<rowWaveBlocks, 256, 0, stream>>>(
                row_start, row_cnt, dstbuf, cur,
                noise + (size_t)k * NN * EMB, nxt, acc, mode);
            unsigned short* t = cur; cur = nxt; nxt = t;
        }
    } else if (ws_size >= required_old) {
        char* p = (char*)d_ws;
        unsigned short* egoA = (unsigned short*)p;  p += EGO_BF;
        unsigned short* egoB = (unsigned short*)p;  p += EGO_BF;
        uint2* bbuf          = (uint2*)p;           p += BBUF;
        int* row_start       = (int*)p;             p += NARR;
        int* row_cnt         = (int*)p;             p += NARR;
        int* bfill           = (int*)p;             p += FARR;

        concat_bf16_kernel<<<vecBlocks, 256, 0, stream>>>(user_emb, item_emb, egoA);
        hipMemsetAsync(bfill, 0, (size_t)NB * NSUB * sizeof(int), stream);
        bucket_scatter_fixed<<<edgeBlocks, 256, 0, stream>>>(rows, cols, vals, bfill, bbuf);
        bucket_sort_fixed<<<NB, 256, 0, stream>>>(bfill, bbuf, row_start, row_cnt);

        unsigned short* cur = egoA;
        unsigned short* nxt = egoB;
        for (int k = 0; k < 3; ++k) {
            int mode = (k == 0) ? 0 : ((k == 2) ? 2 : 1);
            spmm_csr_old<<<rowWaveBlocks, 256, 0, stream>>>(
                row_start, row_cnt, bbuf, cur,
                noise + (size_t)k * NN * EMB, nxt, acc, mode);
            unsigned short* t = cur; cur = nxt; nxt = t;
        }
    } else {
        const size_t EGO_SZ = (size_t)NN * EMB * sizeof(float);
        float* fA = (float*)d_ws;
        float* fB = (float*)((char*)d_ws + EGO_SZ);
        concat_f32_kernel<<<elemBlocks, 256, 0, stream>>>(user_emb, item_emb, fA);
        float* cur = fA; float* nxt = fB;
        for (int k = 0; k < 3; ++k) {
            hipMemsetAsync(nxt, 0, EGO_SZ, stream);
            spmm_atomic_kernel<<<N_EDGES / 4, 256, 0, stream>>>(rows, cols, vals, cur, nxt);
            int mode = (k == 0) ? 0 : ((k == 2) ? 2 : 1);
            noise_acc_kernel<<<elemBlocks, 256, 0, stream>>>(
                nxt, noise + (size_t)k * NN * EMB, acc, mode);
            float* t = cur; cur = nxt; nxt = t;
        }
    }

    hipMemcpyAsync(out + (size_t)NN * EMB, user_proto,
                   (size_t)PROTO * EMB * sizeof(float), hipMemcpyDeviceToDevice, stream);
    hipMemcpyAsync(out + (size_t)NN * EMB + (size_t)PROTO * EMB, item_proto,
                   (size_t)PROTO * EMB * sizeof(float), hipMemcpyDeviceToDevice, stream);
}

// Round 4
// 845.491 us; speedup vs baseline: 1.8661x; 1.1015x over previous
//
#include <hip/hip_runtime.h>

#define USER_NUM 100000
#define ITEM_NUM 50000
#define NN (USER_NUM + ITEM_NUM)
#define EMB 64
#define N_EDGES 8000000
#define EPS_C 0.1f
#define PROTO 4000

// ---------------- old-path params (kept verbatim as ws fallback) ----------------
#define BSHIFT 6
#define BROWS 64                                // rows per bucket
#define NB ((NN + BROWS - 1) / BROWS)           // 2344 buckets
#define NSUB 8
#define CAPS 608
#define WIN (NSUB * CAPS)
#define CAP 4608

// ---------------- hierarchical split params ----------------
#define SBSHIFT 9
#define SBROWS 512                              // rows per super-bin
#define NSB ((NN + SBROWS - 1) / SBROWS)        // 293 super-bins
#define SCAP 28160                              // slots/super-bin; mean 27304, +5.2 sigma
#define SF_STRIDE 16                            // pad sfill counters to one 64B line each
// chunk-sort scatter
#define CHS 8192                                // edges per block chunk (LDS-resident)
#define NCH ((N_EDGES + CHS - 1) / CHS)         // 977 blocks

static __device__ __forceinline__ unsigned short f32_to_bf16_rne(float f) {
    unsigned u = __float_as_uint(f);
    u += 0x7FFFu + ((u >> 16) & 1u);
    return (unsigned short)(u >> 16);
}
static __device__ __forceinline__ float bf16_to_f32(unsigned short h) {
    return __uint_as_float(((unsigned)h) << 16);
}
static __device__ __forceinline__ float bf16_lo(unsigned u) {
    return __uint_as_float(u << 16);
}
static __device__ __forceinline__ float bf16_hi(unsigned u) {
    return __uint_as_float(u & 0xFFFF0000u);
}
static __device__ __forceinline__ unsigned pack_bf16(float lo, float hi) {
    return (unsigned)f32_to_bf16_rne(lo) | ((unsigned)f32_to_bf16_rne(hi) << 16);
}

// ---------- concat + quantize to bf16 (float4 -> ushort4) ----------
__global__ __launch_bounds__(256) void concat_bf16_kernel(const float* __restrict__ u,
                                                          const float* __restrict__ it,
                                                          unsigned short* __restrict__ out) {
    long i4 = (long)blockIdx.x * 256 + threadIdx.x;
    const long usz4 = (long)USER_NUM * EMB / 4;
    const long tot4 = (long)NN * EMB / 4;
    if (i4 >= tot4) return;
    const float4* src = (i4 < usz4) ? (const float4*)u : (const float4*)it;
    long j = (i4 < usz4) ? i4 : (i4 - usz4);
    float4 v = src[j];
    ushort4 o;
    o.x = f32_to_bf16_rne(v.x); o.y = f32_to_bf16_rne(v.y);
    o.z = f32_to_bf16_rne(v.z); o.w = f32_to_bf16_rne(v.w);
    ((ushort4*)out)[i4] = o;
}

// ================= chunk counting-sort scatter (single shot per block) =================
__global__ __launch_bounds__(256) void chunk_sort_scatter(const int* __restrict__ rows,
                                                          const int* __restrict__ cols,
                                                          const float* __restrict__ vals,
                                                          int* __restrict__ sfill,
                                                          uint2* __restrict__ sbuf) {
    __shared__ unsigned skey[CHS];              // 32 KB
    __shared__ unsigned sval[CHS];              // 32 KB
    __shared__ int hist[NSB];
    __shared__ int pref[NSB + 1];
    __shared__ int gbase[NSB];
    __shared__ int fill[NSB];

    const int tid   = threadIdx.x;
    const int start = blockIdx.x * CHS;
    const int n     = (start + CHS <= N_EDGES) ? CHS : (N_EDGES - start);
    const int n4    = n >> 2;                   // all chunk sizes are multiples of 4

    for (int b = tid; b < NSB; b += 256) { hist[b] = 0; fill[b] = 0; }
    __syncthreads();

    // phase 1: histogram (vectorized row read)
    const int4* rows4 = (const int4*)(rows + start);
    for (int i = tid; i < n4; i += 256) {
        int4 r = rows4[i];
        atomicAdd(&hist[r.x >> SBSHIFT], 1);
        atomicAdd(&hist[r.y >> SBSHIFT], 1);
        atomicAdd(&hist[r.z >> SBSHIFT], 1);
        atomicAdd(&hist[r.w >> SBSHIFT], 1);
    }
    __syncthreads();

    // exclusive prefix scan over 293 bins: wave-0 shuffle scan
    if (tid < 64) {
        int carry = 0;
        #pragma unroll
        for (int g = 0; g < (NSB + 63) / 64; ++g) {
            int idx = g * 64 + tid;
            int h = (idx < NSB) ? hist[idx] : 0;
            int v = h;
            #pragma unroll
            for (int off = 1; off < 64; off <<= 1) {
                int t = __shfl_up(v, off, 64);
                if (tid >= off) v += t;
            }
            if (idx < NSB) pref[idx] = carry + v - h;
            carry += __shfl(v, 63, 64);
        }
        if (tid == 0) pref[NSB] = carry;
    }
    __syncthreads();

    // reserve global space: one padded-line atomic per non-empty (block,bin)
    for (int b = tid; b < NSB; b += 256)
        gbase[b] = hist[b] ? atomicAdd(&sfill[b * SF_STRIDE], hist[b]) : 0;

    // phase 2: scatter edges into LDS at sorted positions
    const int4*   cols4 = (const int4*)(cols + start);
    const float4* vals4 = (const float4*)(vals + start);
    for (int i = tid; i < n4; i += 256) {
        int4   r = rows4[i];
        int4   c = cols4[i];
        float4 v = vals4[i];
        {
            int b = r.x >> SBSHIFT; int p = pref[b] + atomicAdd(&fill[b], 1);
            skey[p] = ((unsigned)r.x & (SBROWS - 1)) | ((unsigned)c.x << SBSHIFT);
            sval[p] = __float_as_uint(v.x);
        }
        {
            int b = r.y >> SBSHIFT; int p = pref[b] + atomicAdd(&fill[b], 1);
            skey[p] = ((unsigned)r.y & (SBROWS - 1)) | ((unsigned)c.y << SBSHIFT);
            sval[p] = __float_as_uint(v.y);
        }
        {
            int b = r.z >> SBSHIFT; int p = pref[b] + atomicAdd(&fill[b], 1);
            skey[p] = ((unsigned)r.z & (SBROWS - 1)) | ((unsigned)c.z << SBSHIFT);
            sval[p] = __float_as_uint(v.z);
        }
        {
            int b = r.w >> SBSHIFT; int p = pref[b] + atomicAdd(&fill[b], 1);
            skey[p] = ((unsigned)r.w & (SBROWS - 1)) | ((unsigned)c.w << SBSHIFT);
            sval[p] = __float_as_uint(v.w);
        }
    }
    __syncthreads();

    // phase 3: stream sorted chunk out; consecutive threads -> consecutive slots
    for (int j = tid; j < n; j += 256) {
        int lo = 0, hi = NSB;                   // largest b with pref[b] <= j
        while (hi - lo > 1) {
            int mid = (lo + hi) >> 1;
            if (pref[mid] <= j) lo = mid; else hi = mid;
        }
        int gpos = gbase[lo] + (j - pref[lo]);
        if (gpos < SCAP) {
            uint2 pk; pk.x = skey[j]; pk.y = sval[j];
            sbuf[(size_t)lo * SCAP + gpos] = pk;
        }
    }
}

// ================= per-super-bin row sort (fused) =================
__global__ __launch_bounds__(512) void bin_rowsort(const int* __restrict__ sfill,
                                                   const uint2* __restrict__ sbuf,
                                                   uint2* __restrict__ dst,
                                                   int* __restrict__ row_start,
                                                   int* __restrict__ row_cnt) {
    __shared__ int hist[SBROWS], pref[SBROWS], fill[SBROWS];   // 6 KB
    const int s = blockIdx.x, tid = threadIdx.x;
    int total = sfill[s * SF_STRIDE]; if (total > SCAP) total = SCAP;
    const uint2* src = sbuf + (size_t)s * SCAP;

    for (int r = tid; r < SBROWS; r += 512) { hist[r] = 0; fill[r] = 0; }
    __syncthreads();

    const int n2 = total >> 1;
    const uint4* src4 = (const uint4*)src;      // window base is 16B-aligned
    for (int i = tid; i < n2; i += 512) {
        uint4 q = src4[i];
        atomicAdd(&hist[q.x & (SBROWS - 1)], 1);
        atomicAdd(&hist[q.z & (SBROWS - 1)], 1);
    }
    if (tid == 0 && (total & 1)) atomicAdd(&hist[src[total - 1].x & (SBROWS - 1)], 1);
    __syncthreads();

    if (tid < 64) {
        int carry = 0;
        #pragma unroll
        for (int g = 0; g < SBROWS / 64; ++g) {
            int idx = g * 64 + tid;
            int h = hist[idx];
            int v = h;
            #pragma unroll
            for (int off = 1; off < 64; off <<= 1) {
                int t = __shfl_up(v, off, 64);
                if (tid >= off) v += t;
            }
            pref[idx] = carry + v - h;
            carry += __shfl(v, 63, 64);
        }
    }
    __syncthreads();

    uint2* dwin = dst + (size_t)s * SCAP;
    for (int i = tid; i < n2; i += 512) {
        uint4 q = src4[i];
        {
            int r = (int)(q.x & (SBROWS - 1));
            int p = pref[r] + atomicAdd(&fill[r], 1);
            uint2 o; o.x = q.x >> SBSHIFT; o.y = q.y;   // {col, valbits}
            dwin[p] = o;
        }
        {
            int r = (int)(q.z & (SBROWS - 1));
            int p = pref[r] + atomicAdd(&fill[r], 1);
            uint2 o; o.x = q.z >> SBSHIFT; o.y = q.w;
            dwin[p] = o;
        }
    }
    if (tid == 0 && (total & 1)) {
        uint2 pk = src[total - 1];
        int r = (int)(pk.x & (SBROWS - 1));
        int p = pref[r] + atomicAdd(&fill[r], 1);
        uint2 o; o.x = pk.x >> SBSHIFT; o.y = pk.y;
        dwin[p] = o;
    }
    if (tid < SBROWS) {
        int row = s * SBROWS + tid;
        if (row < NN) { row_start[row] = s * SCAP + pref[tid]; row_cnt[row] = hist[tid]; }
    }
}

// ---------- fused CSR SpMM: 8 edges/wave-instr (8 lanes x 8 bf16 per edge-row) ----------
// slot = lane>>3 picks 1 of 8 concurrent edges; m = lane&7 picks dims 8m..8m+7.
// One csr load covers 8 edges, one uint4 gather covers 8 full x-rows per wave.
// 16-edge unroll keeps 2 csr + 2 gather loads in flight with dual accumulator banks.
__global__ __launch_bounds__(256) void spmm_csr_fused(const int* __restrict__ row_start,
                                                      const int* __restrict__ row_cnt,
                                                      const uint2* __restrict__ csr,
                                                      const unsigned short* __restrict__ x,
                                                      const float* __restrict__ noise_k,
                                                      unsigned short* __restrict__ ego_out,
                                                      float* __restrict__ acc,
                                                      int mode) {
    int row  = (blockIdx.x * 256 + threadIdx.x) >> 6;
    int lane = threadIdx.x & 63;
    if (row >= NN) return;
    const int slot = lane >> 3;                  // 0..7: which edge in the group of 8
    const int m    = lane & 7;                   // dims 8m..8m+7
    const unsigned moff = (unsigned)m << 3;      // element offset within the x row

    int s   = row_start[row];
    int end = s + row_cnt[row];

    float a0 = 0.f, a1 = 0.f, a2 = 0.f, a3 = 0.f;
    float a4 = 0.f, a5 = 0.f, a6 = 0.f, a7 = 0.f;
    float b0 = 0.f, b1 = 0.f, b2 = 0.f, b3 = 0.f;
    float b4 = 0.f, b5 = 0.f, b6 = 0.f, b7 = 0.f;
    int e = s;
    for (; e + 16 <= end; e += 16) {
        uint2 pA = csr[e + slot];
        uint2 pB = csr[e + 8 + slot];
        uint4 gA = *(const uint4*)(x + (((unsigned)pA.x) << 6) + moff);
        uint4 gB = *(const uint4*)(x + (((unsigned)pB.x) << 6) + moff);
        float vA = __uint_as_float(pA.y);
        float vB = __uint_as_float(pB.y);
        a0 += vA * bf16_lo(gA.x); a1 += vA * bf16_hi(gA.x);
        a2 += vA * bf16_lo(gA.y); a3 += vA * bf16_hi(gA.y);
        a4 += vA * bf16_lo(gA.z); a5 += vA * bf16_hi(gA.z);
        a6 += vA * bf16_lo(gA.w); a7 += vA * bf16_hi(gA.w);
        b0 += vB * bf16_lo(gB.x); b1 += vB * bf16_hi(gB.x);
        b2 += vB * bf16_lo(gB.y); b3 += vB * bf16_hi(gB.y);
        b4 += vB * bf16_lo(gB.z); b5 += vB * bf16_hi(gB.z);
        b6 += vB * bf16_lo(gB.w); b7 += vB * bf16_hi(gB.w);
    }
    for (; e < end; e += 8) {                    // masked tail groups of 8
        int idx = e + slot;
        uint2 p = make_uint2(0u, 0u);
        if (idx < end) p = csr[idx];
        uint4 g = *(const uint4*)(x + (((unsigned)p.x) << 6) + moff);
        float v = __uint_as_float(p.y);          // 0 for masked lanes
        a0 += v * bf16_lo(g.x); a1 += v * bf16_hi(g.x);
        a2 += v * bf16_lo(g.y); a3 += v * bf16_hi(g.y);
        a4 += v * bf16_lo(g.z); a5 += v * bf16_hi(g.z);
        a6 += v * bf16_lo(g.w); a7 += v * bf16_hi(g.w);
    }
    a0 += b0; a1 += b1; a2 += b2; a3 += b3;
    a4 += b4; a5 += b5; a6 += b6; a7 += b7;

    // combine the 8 slots: dims 8m..8m+7 summed across slot groups
    #pragma unroll
    for (int off = 8; off < 64; off <<= 1) {
        a0 += __shfl_xor(a0, off, 64);
        a1 += __shfl_xor(a1, off, 64);
        a2 += __shfl_xor(a2, off, 64);
        a3 += __shfl_xor(a3, off, 64);
        a4 += __shfl_xor(a4, off, 64);
        a5 += __shfl_xor(a5, off, 64);
        a6 += __shfl_xor(a6, off, 64);
        a7 += __shfl_xor(a7, off, 64);
    }

    if (slot == 0) {                             // 8 lanes handle the full row, 8 dims each
        size_t base4 = (size_t)row * 16 + ((unsigned)m << 1);   // float4 index
        float4 n0 = ((const float4*)noise_k)[base4];
        float4 n1 = ((const float4*)noise_k)[base4 + 1];
        float ss = n0.x * n0.x + n0.y * n0.y + n0.z * n0.z + n0.w * n0.w
                 + n1.x * n1.x + n1.y * n1.y + n1.z * n1.z + n1.w * n1.w;
        #pragma unroll
        for (int off = 1; off < 8; off <<= 1) ss += __shfl_xor(ss, off, 64);
        float inv = EPS_C / fmaxf(sqrtf(ss), 1e-12f);

        float e0 = fmaf(((a0 > 0.f) ? 1.f : ((a0 < 0.f) ? -1.f : 0.f)) * n0.x, inv, a0);
        float e1 = fmaf(((a1 > 0.f) ? 1.f : ((a1 < 0.f) ? -1.f : 0.f)) * n0.y, inv, a1);
        float e2 = fmaf(((a2 > 0.f) ? 1.f : ((a2 < 0.f) ? -1.f : 0.f)) * n0.z, inv, a2);
        float e3 = fmaf(((a3 > 0.f) ? 1.f : ((a3 < 0.f) ? -1.f : 0.f)) * n0.w, inv, a3);
        float e4 = fmaf(((a4 > 0.f) ? 1.f : ((a4 < 0.f) ? -1.f : 0.f)) * n1.x, inv, a4);
        float e5 = fmaf(((a5 > 0.f) ? 1.f : ((a5 < 0.f) ? -1.f : 0.f)) * n1.y, inv, a5);
        float e6 = fmaf(((a6 > 0.f) ? 1.f : ((a6 < 0.f) ? -1.f : 0.f)) * n1.z, inv, a6);
        float e7 = fmaf(((a7 > 0.f) ? 1.f : ((a7 < 0.f) ? -1.f : 0.f)) * n1.w, inv, a7);

        uint4 o;
        o.x = pack_bf16(e0, e1); o.y = pack_bf16(e2, e3);
        o.z = pack_bf16(e4, e5); o.w = pack_bf16(e6, e7);
        ((uint4*)ego_out)[(size_t)row * 8 + m] = o;

        float4* accp = (float4*)acc + base4;
        if (mode == 0) {
            accp[0] = make_float4(e0, e1, e2, e3);
            accp[1] = make_float4(e4, e5, e6, e7);
        } else if (mode == 1) {
            float4 c0 = accp[0], c1 = accp[1];
            c0.x += e0; c0.y += e1; c0.z += e2; c0.w += e3;
            c1.x += e4; c1.y += e5; c1.z += e6; c1.w += e7;
            accp[0] = c0; accp[1] = c1;
        } else {
            float4 c0 = accp[0], c1 = accp[1];
            c0.x = (c0.x + e0) * (1.0f / 3.0f); c0.y = (c0.y + e1) * (1.0f / 3.0f);
            c0.z = (c0.z + e2) * (1.0f / 3.0f); c0.w = (c0.w + e3) * (1.0f / 3.0f);
            c1.x = (c1.x + e4) * (1.0f / 3.0f); c1.y = (c1.y + e5) * (1.0f / 3.0f);
            c1.z = (c1.z + e6) * (1.0f / 3.0f); c1.w = (c1.w + e7) * (1.0f / 3.0f);
            accp[0] = c0; accp[1] = c1;
        }
    }
}

// ================= OLD PATH (verbatim fallback) =================
__global__ __launch_bounds__(256) void bucket_scatter_fixed(const int* __restrict__ rows,
                                                            const int* __restrict__ cols,
                                                            const float* __restrict__ vals,
                                                            int* __restrict__ bfill,
                                                            uint2* __restrict__ bbuf) {
    int e = blockIdx.x * 256 + threadIdx.x;
    if (e >= N_EDGES) return;
    int sub = blockIdx.x & (NSUB - 1);
    int r = rows[e];
    int b = r >> BSHIFT;
    int pos = atomicAdd(&bfill[b * NSUB + sub], 1);
    if (pos < CAPS) {
        uint2 pk;
        pk.x = (unsigned)(r & (BROWS - 1)) | ((unsigned)cols[e] << BSHIFT);
        pk.y = __float_as_uint(vals[e]);
        bbuf[(size_t)b * WIN + sub * CAPS + pos] = pk;
    }
}

__global__ __launch_bounds__(256) void bucket_sort_fixed(const int* __restrict__ bfill,
                                                         uint2* __restrict__ bbuf,
                                                         int* __restrict__ row_start,
                                                         int* __restrict__ row_cnt) {
    __shared__ uint2 buf[CAP];
    __shared__ int scnt[NSUB], soff[NSUB];
    __shared__ int h[BROWS], pref[BROWS], fill[BROWS];
    int b = blockIdx.x;
    int tid = threadIdx.x;
    if (tid < NSUB) {
        int c = bfill[b * NSUB + tid];
        scnt[tid] = (c < CAPS) ? c : CAPS;
    }
    if (tid < BROWS) { h[tid] = 0; fill[tid] = 0; }
    __syncthreads();
    if (tid == 0) {
        int run = 0;
        #pragma unroll
        for (int s = 0; s < NSUB; ++s) { soff[s] = run; run += scnt[s]; }
    }
    __syncthreads();
    int total = soff[NSUB - 1] + scnt[NSUB - 1];
    if (total > CAP) total = CAP;
    for (int s = 0; s < NSUB; ++s) {
        int c = scnt[s], off = soff[s];
        const uint2* src = bbuf + (size_t)b * WIN + s * CAPS;
        for (int i = tid; i < c; i += 256)
            if (off + i < CAP) buf[off + i] = src[i];
    }
    __syncthreads();
    for (int i = tid; i < total; i += 256) atomicAdd(&h[buf[i].x & (BROWS - 1)], 1);
    __syncthreads();
    if (tid == 0) {
        int run = 0;
        #pragma unroll
        for (int r = 0; r < BROWS; ++r) { pref[r] = run; run += h[r]; }
    }
    __syncthreads();
    uint2* dst = bbuf + (size_t)b * WIN;
    for (int i = tid; i < total; i += 256) {
        unsigned m = buf[i].x;
        int rl = (int)(m & (BROWS - 1));
        int pos = pref[rl] + atomicAdd(&fill[rl], 1);
        uint2 pk;
        pk.x = m >> BSHIFT;
        pk.y = buf[i].y;
        dst[pos] = pk;
    }
    if (tid < BROWS) {
        int row = b * BROWS + tid;
        if (row < NN) { row_start[row] = b * WIN + pref[tid]; row_cnt[row] = h[tid]; }
    }
}

// old-path spmm (wave-per-row, scalar bf16 gather) — kept for fallback branch
__global__ __launch_bounds__(256) void spmm_csr_old(const int* __restrict__ row_start,
                                                    const int* __restrict__ row_cnt,
                                                    const uint2* __restrict__ csr,
                                                    const unsigned short* __restrict__ x,
                                                    const float* __restrict__ noise_k,
                                                    unsigned short* __restrict__ ego_out,
                                                    float* __restrict__ acc,
                                                    int mode) {
    int row = (blockIdx.x * 256 + threadIdx.x) >> 6;
    int lane = threadIdx.x & 63;
    if (row >= NN) return;
    int s = row_start[row];
    int end = s + row_cnt[row];
    float a0 = 0.f, a1 = 0.f, a2 = 0.f, a3 = 0.f;
    int e = s;
    for (; e + 4 <= end; e += 4) {
        uint2 p0 = csr[e], p1 = csr[e + 1], p2 = csr[e + 2], p3 = csr[e + 3];
        a0 += __uint_as_float(p0.y) * bf16_to_f32(x[(size_t)p0.x * EMB + lane]);
        a1 += __uint_as_float(p1.y) * bf16_to_f32(x[(size_t)p1.x * EMB + lane]);
        a2 += __uint_as_float(p2.y) * bf16_to_f32(x[(size_t)p2.x * EMB + lane]);
        a3 += __uint_as_float(p3.y) * bf16_to_f32(x[(size_t)p3.x * EMB + lane]);
    }
    for (; e < end; ++e) {
        uint2 p = csr[e];
        a0 += __uint_as_float(p.y) * bf16_to_f32(x[(size_t)p.x * EMB + lane]);
    }
    float a = (a0 + a1) + (a2 + a3);
    size_t idx = (size_t)row * EMB + lane;
    float nv = noise_k[idx];
    float ss = nv * nv;
    #pragma unroll
    for (int off = 32; off >= 1; off >>= 1) ss += __shfl_xor(ss, off, 64);
    float nrm = fmaxf(sqrtf(ss), 1e-12f);
    float sgn = (a > 0.0f) ? 1.0f : ((a < 0.0f) ? -1.0f : 0.0f);
    float e1 = a + sgn * (nv / nrm) * EPS_C;
    ego_out[idx] = f32_to_bf16_rne(e1);
    if (mode == 0)      acc[idx] = e1;
    else if (mode == 1) acc[idx] += e1;
    else                acc[idx] = (acc[idx] + e1) * (1.0f / 3.0f);
}

// ---------- fallback: fp32 atomic path (needs 76.8 MB ws) ----------
__global__ __launch_bounds__(256) void concat_f32_kernel(const float* __restrict__ u,
                                                         const float* __restrict__ it,
                                                         float* __restrict__ out) {
    long i = (long)blockIdx.x * 256 + threadIdx.x;
    const long usz = (long)USER_NUM * EMB;
    const long tot = (long)NN * EMB;
    if (i >= tot) return;
    out[i] = (i < usz) ? u[i] : it[i - usz];
}

__global__ __launch_bounds__(256) void spmm_atomic_kernel(const int* __restrict__ rows,
                                                          const int* __restrict__ cols,
                                                          const float* __restrict__ vals,
                                                          const float* __restrict__ x,
                                                          float* __restrict__ y) {
    long t = (long)blockIdx.x * 256 + threadIdx.x;
    int e = (int)(t >> 6);
    int lane = (int)(t & 63);
    if (e >= N_EDGES) return;
    atomicAdd(&y[(long)rows[e] * EMB + lane], vals[e] * x[(long)cols[e] * EMB + lane]);
}

__global__ __launch_bounds__(256) void noise_acc_kernel(float* __restrict__ ego,
                                                        const float* __restrict__ noise_k,
                                                        float* __restrict__ acc,
                                                        int mode) {
    long t = (long)blockIdx.x * 256 + threadIdx.x;
    int node = (int)(t >> 6);
    int lane = (int)(t & 63);
    if (node >= NN) return;
    long idx = (long)node * EMB + lane;
    float nv = noise_k[idx];
    float s = nv * nv;
    #pragma unroll
    for (int off = 32; off >= 1; off >>= 1) s += __shfl_xor(s, off, 64);
    float nrm = fmaxf(sqrtf(s), 1e-12f);
    float e0 = ego[idx];
    float sgn = (e0 > 0.0f) ? 1.0f : ((e0 < 0.0f) ? -1.0f : 0.0f);
    float e1 = e0 + sgn * (nv / nrm) * EPS_C;
    ego[idx] = e1;
    if (mode == 0)      acc[idx] = e1;
    else if (mode == 1) acc[idx] += e1;
    else                acc[idx] = (acc[idx] + e1) * (1.0f / 3.0f);
}

extern "C" void kernel_launch(void* const* d_in, const int* in_sizes, int n_in,
                              void* d_out, int out_size, void* d_ws, size_t ws_size,
                              hipStream_t stream) {
    const float* user_emb   = (const float*)d_in[0];
    const float* item_emb   = (const float*)d_in[1];
    const float* user_proto = (const float*)d_in[2];
    const float* item_proto = (const float*)d_in[3];
    const int*   rows       = (const int*)d_in[4];
    const int*   cols       = (const int*)d_in[5];
    const float* vals       = (const float*)d_in[6];
    const float* noise      = (const float*)d_in[7];
    float* out = (float*)d_out;

    const size_t EGO_BF = ((size_t)NN * EMB * sizeof(unsigned short) + 255) & ~(size_t)255;
    const size_t NARR   = ((size_t)NN * sizeof(int) + 255) & ~(size_t)255;

    // ---- new path layout (~172 MB) ----
    const size_t SBUF_SZ  = (size_t)NSB * SCAP * sizeof(uint2);      // 66.0 MB
    const size_t DST_SZ   = (size_t)NSB * SCAP * sizeof(uint2);      // 66.0 MB (row-sorted)
    const size_t SFILL_SZ = ((size_t)NSB * SF_STRIDE * sizeof(int) + 255) & ~(size_t)255;
    const size_t required_new = 2 * EGO_BF + SBUF_SZ + DST_SZ + 2 * NARR + SFILL_SZ;

    // ---- old path layout (~131 MB) ----
    const size_t BBUF   = (size_t)NB * WIN * sizeof(uint2);
    const size_t FARR   = ((size_t)NB * NSUB * sizeof(int) + 255) & ~(size_t)255;
    const size_t required_old = 2 * EGO_BF + BBUF + 2 * NARR + FARR;

    float* acc = out;
    const int elemTotal  = NN * EMB;
    const int elemBlocks = (elemTotal + 255) / 256;
    const int vecBlocks  = (elemTotal / 4 + 255) / 256;
    const int edgeBlocks = (N_EDGES + 255) / 256;
    const int rowWaveBlocks = (NN + 3) / 4;

    if (ws_size >= required_new) {
        char* p = (char*)d_ws;
        unsigned short* egoA = (unsigned short*)p;  p += EGO_BF;
        unsigned short* egoB = (unsigned short*)p;  p += EGO_BF;
        uint2* sbuf          = (uint2*)p;           p += SBUF_SZ;
        uint2* dstbuf        = (uint2*)p;           p += DST_SZ;
        int* row_start       = (int*)p;             p += NARR;
        int* row_cnt         = (int*)p;             p += NARR;
        int* sfill           = (int*)p;             p += SFILL_SZ;

        concat_bf16_kernel<<<vecBlocks, 256, 0, stream>>>(user_emb, item_emb, egoA);
        hipMemsetAsync(sfill, 0, (size_t)NSB * SF_STRIDE * sizeof(int), stream);
        chunk_sort_scatter<<<NCH, 256, 0, stream>>>(rows, cols, vals, sfill, sbuf);
        bin_rowsort<<<NSB, 512, 0, stream>>>(sfill, sbuf, dstbuf, row_start, row_cnt);

        unsigned short* cur = egoA;
        unsigned short* nxt = egoB;
        for (int k = 0; k < 3; ++k) {
            int mode = (k == 0) ? 0 : ((k == 2) ? 2 : 1);
            spmm_csr_fused<<<rowWaveBlocks, 256, 0, stream>>>(
                row_start, row_cnt, dstbuf, cur,
                noise + (size_t)k * NN * EMB, nxt, acc, mode);
            unsigned short* t = cur; cur = nxt; nxt = t;
        }
    } else if (ws_size >= required_old) {
        char* p = (char*)d_ws;
        unsigned short* egoA = (unsigned short*)p;  p += EGO_BF;
        unsigned short* egoB = (unsigned short*)p;  p += EGO_BF;
        uint2* bbuf          = (uint2*)p;           p += BBUF;
        int* row_start       = (int*)p;             p += NARR;
        int* row_cnt         = (int*)p;             p += NARR;
        int* bfill           = (int*)p;             p += FARR;

        concat_bf16_kernel<<<vecBlocks, 256, 0, stream>>>(user_emb, item_emb, egoA);
        hipMemsetAsync(bfill, 0, (size_t)NB * NSUB * sizeof(int), stream);
        bucket_scatter_fixed<<<edgeBlocks, 256, 0, stream>>>(rows, cols, vals, bfill, bbuf);
        bucket_sort_fixed<<<NB, 256, 0, stream>>>(bfill, bbuf, row_start, row_cnt);

        unsigned short* cur = egoA;
        unsigned short* nxt = egoB;
        for (int k = 0; k < 3; ++k) {
            int mode = (k == 0) ? 0 : ((k == 2) ? 2 : 1);
            spmm_csr_old<<<rowWaveBlocks, 256, 0, stream>>>(
                row_start, row_cnt, bbuf, cur,
                noise + (size_t)k * NN * EMB, nxt, acc, mode);
            unsigned short* t = cur; cur = nxt; nxt = t;
        }
    } else {
        const size_t EGO_SZ = (size_t)NN * EMB * sizeof(float);
        float* fA = (float*)d_ws;
        float* fB = (float*)((char*)d_ws + EGO_SZ);
        concat_f32_kernel<<<elemBlocks, 256, 0, stream>>>(user_emb, item_emb, fA);
        float* cur = fA; float* nxt = fB;
        for (int k = 0; k < 3; ++k) {
            hipMemsetAsync(nxt, 0, EGO_SZ, stream);
            spmm_atomic_kernel<<<N_EDGES / 4, 256, 0, stream>>>(rows, cols, vals, cur, nxt);
            int mode = (k == 0) ? 0 : ((k == 2) ? 2 : 1);
            noise_acc_kernel<<<elemBlocks, 256, 0, stream>>>(
                nxt, noise + (size_t)k * NN * EMB, acc, mode);
            float* t = cur; cur = nxt; nxt = t;
        }
    }

    hipMemcpyAsync(out + (size_t)NN * EMB, user_proto,
                   (size_t)PROTO * EMB * sizeof(float), hipMemcpyDeviceToDevice, stream);
    hipMemcpyAsync(out + (size_t)NN * EMB + (size_t)PROTO * EMB, item_proto,
                   (size_t)PROTO * EMB * sizeof(float), hipMemcpyDeviceToDevice, stream);
}